// Round 11
// baseline (123273.035 us; speedup 1.0000x reference)
//
#include <hip/hip_runtime.h>
#include <hip/hip_cooperative_groups.h>
#include <math.h>

namespace cg = cooperative_groups;

#define BB 64
#define TT 128
#define DBX 256
#define IND 264
#define HS 512
#define NH 4
#define MMM 128
#define AAA 2048
#define PPH 390
#define NCOLS 2072
#define KSPL 8
#define KCH  161
#define EPSF 1e-8f

__device__ __forceinline__ float sigmf(float x){ return 1.0f/(1.0f+expf(-x)); }
__device__ __forceinline__ float softplusf(float x){ return (x > 20.0f) ? x : log1pf(expf(x)); }
__device__ __forceinline__ float wred64(float v){
  #pragma unroll
  for (int off=32; off>0; off>>=1) v += __shfl_xor(v, off);
  return v;
}

// ---------------- transpose x[b][t][i] -> xT[t*IND+i][b] (once) ----------------
__global__ __launch_bounds__(256) void k_tx(const float* __restrict__ x, float* __restrict__ xT){
  int b = blockIdx.x;
  for (int f = threadIdx.x; f < TT*IND; f += 256)
    xT[(size_t)f*BB + b] = x[(size_t)b*TT*IND + f];
}

// ================= persistent cooperative kernel =================
// 256 blocks x 512 threads, 1 block/CU. 8 waves/CU x 256 VGPR = full 2048-reg pool.
// block = (b, q): b = bid>>2, q = bid&3. Thread owns col = q*512+tid: mem[128] in regs.
__global__ __launch_bounds__(512, 1) void k_persist(
    const float* __restrict__ xT, const float* __restrict__ Wst, const float* __restrict__ bst,
    const float* __restrict__ Wout, const float* __restrict__ bout,
    const float* __restrict__ Wupd, const float* __restrict__ bupd,
    float* __restrict__ out,
    float* __restrict__ hT, float* __restrict__ readT, float* __restrict__ hpart,
    float* __restrict__ kvec_t, float* __restrict__ beta, float* __restrict__ gbuf,
    float* __restrict__ gam, float* __restrict__ shraw,
    float* __restrict__ erase, float* __restrict__ addb,
    float* __restrict__ wcsum, float* __restrict__ wpsum,
    float* __restrict__ haloL, float* __restrict__ haloR)
{
  cg::grid_group grid = cg::this_grid();
  __shared__ float sm[11584];   // 46.3 KB static (P6 peak)
  const int bid = blockIdx.x, tid = threadIdx.x;
  const int b = bid >> 2, q = bid & 3;
  const int col = q*512 + tid;
  const int lane = tid & 63, wave = tid >> 6;   // 8 waves

  float mem[128];
  #pragma unroll
  for (int m=0;m<128;++m) mem[m] = 0.01f;
  float wt[4];
  #pragma unroll
  for (int h=0;h<4;++h) wt[h] = (col==0)?1.0f:0.0f;
  float e_r[4], wp_r[4];

  // P1: 2048 tasks (512 j x 4 kq) over 2048 waves -> 1 task/wave
  const int task1 = bid*8 + wave;
  const int j1 = task1 >> 2, kq1 = task1 & 3, k01 = kq1*322;
  // P3: 2072 cols over 2048 waves: col w, plus w<24 also col 2048+w
  const int w3 = bid*8 + wave;

  for (int t=0; t<TT; ++t){
    // ======== P1: controller state GEMV partial (+zero wcsum/wpsum) ========
    {
      if (bid == 0 && tid < 256) wcsum[tid] = 0.0f;
      if (bid == 1 && tid < 256) wpsum[tid] = 0.0f;
      const float* xt  = xT + (size_t)t*IND*BB;
      const float* hTp = hT + ((t+1)&1)*HS*BB;
      const float* rTp = readT + (t&1)*HS*BB;
      const int kend = k01 + 322;
      float a0 = 0.0f;
      { int s_ = k01, e_ = kend < IND ? kend : IND;
        #pragma unroll 4
        for (int k=s_; k<e_; ++k) a0 += xt[k*BB+lane]*Wst[(size_t)k*HS + j1]; }
      { int s_ = k01 > IND ? k01 : IND, e_ = kend < (IND+HS) ? kend : (IND+HS);
        if (t == 0){
          #pragma unroll 4
          for (int k=s_; k<e_; ++k) a0 += Wst[(size_t)k*HS + j1];          // h0 = 1
        } else {
          #pragma unroll 4
          for (int k=s_; k<e_; ++k) a0 += hTp[(k-IND)*BB+lane]*Wst[(size_t)k*HS + j1];
        } }
      { int s_ = k01 > (IND+HS) ? k01 : (IND+HS);
        if (t == 0){
          #pragma unroll 4
          for (int k=s_; k<kend; ++k) a0 += 0.01f*Wst[(size_t)k*HS + j1];  // read0 = 0.01
        } else {
          #pragma unroll 4
          for (int k=s_; k<kend; ++k) a0 += rTp[(k-IND-HS)*BB+lane]*Wst[(size_t)k*HS + j1];
        } }
      hpart[(size_t)kq1*HS*BB + j1*BB + lane] = a0;
    }
    grid.sync();

    // ======== P2: h finalize + zero next read accumulator ========
    {
      int gid = bid*512 + tid;    // 0..131071
      if (gid < HS*BB){
        float v = hpart[gid] + hpart[HS*BB+gid] + hpart[2*HS*BB+gid] + hpart[3*HS*BB+gid];
        hT[(t&1)*HS*BB + gid] = sigmf(v + bst[gid>>6]);
      } else if (gid < 2*HS*BB){
        readT[((t+1)&1)*HS*BB + (gid - HS*BB)] = 0.0f;
      }
    }
    grid.sync();

    // ======== P3: out/upd GEMV + per-head transforms ========
    {
      const float* hc = hT + (t&1)*HS*BB;
      #pragma unroll
      for (int rep=0; rep<2; ++rep){
        int c = (rep==0) ? w3 : 2048 + w3;
        if (rep==1 && w3 >= NCOLS-2048) break;
        const float* wcol; int strd; float v;
        if (c < DBX){ wcol = Wout + c; strd = DBX; v = bout[c]; }
        else        { wcol = Wupd + (c-DBX); strd = NH*PPH; v = bupd[c-DBX]; }
        #pragma unroll 4
        for (int k=0; k<HS; ++k) v += hc[k*BB+lane]*wcol[(size_t)k*strd];
        if (c < DBX){
          out[((size_t)lane*TT + t)*DBX + c] = sigmf(v);
        } else {
          int u2 = c - DBX; int hh = u2/PPH; int p = u2 - hh*PPH;
          if (p < MMM)            kvec_t[lane*HS + p*NH + hh] = v;
          else if (p == MMM)      beta[lane*NH+hh] = softplusf(v);
          else if (p == MMM+1)    gbuf[lane*NH+hh] = sigmf(v);
          else if (p <  MMM+5)    shraw[(lane*NH+hh)*3 + (p-(MMM+2))] = v;
          else if (p == MMM+5)    gam[lane*NH+hh] = 1.0f + softplusf(v);
          else if (p <  2*MMM+6)  erase[lane*HS + hh*MMM + (p-(MMM+6))] = sigmf(v);
          else                    addb[lane*HS + hh*MMM + (p-(2*MMM+6))] = tanhf(v);
        }
      }
    }
    grid.sync();

    // ======== P4: content dots + e + wcsum + halo ========
    {
      float* kl  = sm;         // [512] layout [m*4+h]
      float* red = sm + 512;   // [512]
      float* pb  = sm + 1024;  // [4]
      float* knl = sm + 1028;  // [4]
      float* wsr = sm + 1032;  // [32]
      kl[tid] = kvec_t[b*HS + tid];
      if (tid < 4) pb[tid] = beta[b*NH + tid];
      __syncthreads();
      red[tid] = kl[tid]*kl[tid];
      __syncthreads();
      for (int off=256; off>=4; off>>=1){
        if (tid < off) red[tid] += red[tid+off];
        __syncthreads();
      }
      if (tid < 4) knl[tid] = sqrtf(red[tid]);
      __syncthreads();
      const float4* kl4 = (const float4*)kl;
      float d0=0,d1=0,d2=0,d3=0,n2=0;
      #pragma unroll
      for (int m=0; m<128; ++m){
        float4 kv = kl4[m];
        float mv = mem[m];
        d0 += kv.x*mv; d1 += kv.y*mv; d2 += kv.z*mv; d3 += kv.w*mv;
        n2 += mv*mv;
      }
      float mn = sqrtf(n2);
      float dd[4] = {d0,d1,d2,d3};
      #pragma unroll
      for (int h=0; h<4; ++h)
        e_r[h] = expf(pb[h] * (dd[h]/(knl[h]*mn + EPSF)));
      #pragma unroll
      for (int h=0; h<4; ++h){
        float v = wred64(e_r[h]);
        if (lane == 0) wsr[wave*4+h] = v;
      }
      __syncthreads();
      if (tid < 4){
        float s2 = 0.0f;
        #pragma unroll
        for (int w=0; w<8; ++w) s2 += wsr[w*4+tid];
        atomicAdd(&wcsum[b*NH+tid], s2);
      }
      if (tid == 0){
        #pragma unroll
        for (int h=0;h<4;++h){ haloL[bid*8+h] = e_r[h]; haloL[bid*8+4+h] = wt[h]; }
      }
      if (tid == 511){
        #pragma unroll
        for (int h=0;h<4;++h){ haloR[bid*8+h] = e_r[h]; haloR[bid*8+4+h] = wt[h]; }
      }
    }
    grid.sync();

    // ======== P5: normalize + interpolate + shift + sharpen + wpsum ========
    {
      float (*ew)[9] = (float(*)[9])sm;    // [512][9] = 4608
      float* sh  = sm + 4608;  // [12]
      float* gg  = sm + 4620;  // [4]
      float* gm  = sm + 4624;  // [4]
      float* wci = sm + 4628;  // [4]
      float* wsr = sm + 4632;  // [32]
      #pragma unroll
      for (int h=0;h<4;++h){ ew[tid][h] = e_r[h]; ew[tid][4+h] = wt[h]; }
      if (tid < 4){
        gg[tid] = gbuf[b*NH+tid];
        gm[tid] = gam[b*NH+tid];
        wci[tid] = 1.0f/wcsum[b*NH+tid];
        float s0 = shraw[(b*NH+tid)*3], s1 = shraw[(b*NH+tid)*3+1], s2 = shraw[(b*NH+tid)*3+2];
        float mx = fmaxf(s0, fmaxf(s1, s2));
        float e0 = expf(s0-mx), e1 = expf(s1-mx), e2 = expf(s2-mx);
        float inv = 1.0f/(e0+e1+e2);
        sh[tid*3] = e0*inv; sh[tid*3+1] = e1*inv; sh[tid*3+2] = e2*inv;
      }
      __syncthreads();
      #pragma unroll
      for (int h=0; h<4; ++h){
        float eL, wL, eR, wR;
        if (tid == 0){
          const float* hb = haloR + (b*4 + ((q+3)&3))*8;
          eL = hb[h]; wL = hb[4+h];
        } else { eL = ew[tid-1][h]; wL = ew[tid-1][4+h]; }
        if (tid == 511){
          const float* hb = haloL + (b*4 + ((q+1)&3))*8;
          eR = hb[h]; wR = hb[4+h];
        } else { eR = ew[tid+1][h]; wR = ew[tid+1][4+h]; }
        float g = gg[h], inv = wci[h];
        float wg0 = g*e_r[h]*inv + (1.0f-g)*wt[h];
        float wgL = g*eL*inv     + (1.0f-g)*wL;
        float wgR = g*eR*inv     + (1.0f-g)*wR;
        float ws = sh[h*3]*wgR + sh[h*3+1]*wg0 + sh[h*3+2]*wgL;
        wp_r[h] = powf(ws + EPSF, gm[h]);
      }
      #pragma unroll
      for (int h=0; h<4; ++h){
        float v = wred64(wp_r[h]);
        if (lane == 0) wsr[wave*4+h] = v;
      }
      __syncthreads();
      if (tid < 4){
        float s3 = 0.0f;
        #pragma unroll
        for (int w=0; w<8; ++w) s3 += wsr[w*4+tid];
        atomicAdd(&wpsum[b*NH+tid], s3);
      }
    }
    grid.sync();

    // ======== P6: wt_new + mem update (regs) + read einsum (padded LDS transpose) ========
    {
      float* erT = sm;          // [512] [m*4+h]
      float* adT = sm + 512;    // [512]
      float* wlT = sm + 1024;   // [4][528] padded per-col weights
      float* M   = sm + 3136;   // [16][528] = 8448 -> total 11584
      #pragma unroll
      for (int h=0;h<4;++h) wt[h] = wp_r[h] / wpsum[b*NH+h];
      {
        int m0 = tid >> 2, h0 = tid & 3;
        erT[tid] = erase[b*HS + h0*MMM + m0];   // erT[m*4+h]
        adT[tid] = addb [b*HS + h0*MMM + m0];
      }
      const int pa = tid + ((tid>>7)<<2);       // padded col index (pad 4 per 128)
      #pragma unroll
      for (int h=0;h<4;++h) wlT[h*528 + pa] = wt[h];
      __syncthreads();
      const float4* e4 = (const float4*)erT;
      const float4* a4 = (const float4*)adT;
      #pragma unroll
      for (int m=0; m<128; ++m){
        float4 ev = e4[m], av = a4[m];
        float et = (1.0f - ev.x*wt[0])*(1.0f - ev.y*wt[1])
                 * (1.0f - ev.z*wt[2])*(1.0f - ev.w*wt[3]);
        float at = av.x*wt[0] + av.y*wt[1] + av.z*wt[2] + av.w*wt[3];
        mem[m] = mem[m]*et + at;
      }
      float* rT = readT + ((t+1)&1)*HS*BB;
      const int task = tid >> 3, qq = tid & 7;  // task 0..63: row=task>>2, hh=task&3
      const int row = task >> 2, hh = task & 3;
      const int cs = qq*64 + ((qq>>1)<<2);      // padded chunk start (64 data cols)
      #pragma unroll
      for (int st=0; st<8; ++st){
        __syncthreads();
        #pragma unroll
        for (int r=0; r<16; ++r) M[r*528 + pa] = mem[st*16 + r];
        __syncthreads();
        float acc = 0.0f;
        #pragma unroll
        for (int j4=0; j4<16; ++j4){
          float4 mv = *(const float4*)&M[row*528 + cs + j4*4];
          float4 wv = *(const float4*)&wlT[hh*528 + cs + j4*4];
          acc += mv.x*wv.x + mv.y*wv.y + mv.z*wv.z + mv.w*wv.w;
        }
        acc += __shfl_xor(acc, 1);
        acc += __shfl_xor(acc, 2);
        acc += __shfl_xor(acc, 4);
        if (qq == 0)
          atomicAdd(&rT[(hh*MMM + st*16 + row)*BB + b], acc);
      }
    }
    grid.sync();
  }
}

// ================= fallback: round-6 verified pipeline =================
__global__ void k_init(float* __restrict__ hT, float* __restrict__ readT,
                       float* __restrict__ wt, float* __restrict__ mem){
  int i = blockIdx.x*blockDim.x + threadIdx.x;
  int stride = gridDim.x*blockDim.x;
  for (int idx=i; idx<BB*MMM*AAA; idx+=stride) mem[idx]=0.01f;
  for (int idx=i; idx<HS*BB; idx+=stride){ hT[idx]=1.0f; readT[idx]=0.01f; }
  for (int idx=i; idx<BB*NH*AAA; idx+=stride) wt[idx] = ((idx & (AAA-1))==0)?1.0f:0.0f;
}

__global__ __launch_bounds__(256) void k1_state(
    const float* __restrict__ xT, const float* __restrict__ Wst,
    const float* __restrict__ hTp, const float* __restrict__ readTp,
    float* __restrict__ hpart, float* __restrict__ wcsum, float* __restrict__ wpsum, int t)
{
  int tid = threadIdx.x, wave = tid>>6, lane = tid&63;
  int ks = blockIdx.y;
  int j0 = blockIdx.x*16 + wave*4;
  if (blockIdx.x==0 && ks==0){
    wcsum[tid] = 0.0f;
    wpsum[tid] = 0.0f;
  }
  float a0=0,a1=0,a2=0,a3=0;
  int k0 = ks*KCH, kend = k0+KCH;

  #define K1STEP(AEXPR) { float aV=(AEXPR); \
      float4 wv = *(const float4*)(Wst + (size_t)k*HS + j0); \
      a0 += aV*wv.x; a1 += aV*wv.y; a2 += aV*wv.z; a3 += aV*wv.w; }

  {int s = k0, e = kend<IND?kend:IND;
   #pragma unroll 4
   for (int k=s;k<e;++k) K1STEP(xT[((size_t)t*IND + k)*BB + lane]); }
  {int s = k0>IND?k0:IND, e = kend<(IND+HS)?kend:(IND+HS);
   #pragma unroll 4
   for (int k=s;k<e;++k) K1STEP(hTp[(k-IND)*BB + lane]); }
  {int s = k0>(IND+HS)?k0:(IND+HS), e = kend;
   #pragma unroll 4
   for (int k=s;k<e;++k) K1STEP(readTp[(k-IND-HS)*BB + lane]); }
  #undef K1STEP

  float* hp = hpart + (size_t)ks*HS*BB + (size_t)j0*BB + lane;
  hp[0]    = a0;
  hp[BB]   = a1;
  hp[2*BB] = a2;
  hp[3*BB] = a3;
}

__global__ __launch_bounds__(512) void k2h(
    const float* __restrict__ hpart, const float* __restrict__ bst, float* __restrict__ hTn)
{
  int idx = blockIdx.x*512 + threadIdx.x;
  float v = 0.0f;
  #pragma unroll
  for (int ks=0; ks<KSPL; ++ks) v += hpart[(size_t)ks*HS*BB + idx];
  hTn[idx] = sigmf(v + bst[idx>>6]);
}

__global__ __launch_bounds__(256) void k2_outupd(
    const float* __restrict__ hTn,
    const float* __restrict__ Wout, const float* __restrict__ bout,
    const float* __restrict__ Wupd, const float* __restrict__ bupd,
    float* __restrict__ out,
    float* __restrict__ kvec_t, float* __restrict__ beta, float* __restrict__ gbuf,
    float* __restrict__ gam, float* __restrict__ shraw,
    float* __restrict__ erase, float* __restrict__ addb, int t)
{
  __shared__ float part[4][8][BB];
  int tid = threadIdx.x, ks = tid>>6, lane = tid&63;
  int c0 = blockIdx.x*8;
  bool isout = (c0 < DBX);
  size_t strd = isout ? (size_t)DBX : (size_t)(NH*PPH);
  const float* wbase = isout ? (Wout + c0) : (Wupd + (c0 - DBX));
  bool valid = (c0 < NCOLS);

  float acc[8] = {0,0,0,0,0,0,0,0};
  if (valid){
    int k0 = ks*128;
    #pragma unroll 4
    for (int k=k0; k<k0+128; ++k){
      float a = hTn[k*BB + lane];
      const float4* w4 = (const float4*)(wbase + (size_t)k*strd);
      float4 wa = w4[0], wb = w4[1];
      acc[0]+=a*wa.x; acc[1]+=a*wa.y; acc[2]+=a*wa.z; acc[3]+=a*wa.w;
      acc[4]+=a*wb.x; acc[5]+=a*wb.y; acc[6]+=a*wb.z; acc[7]+=a*wb.w;
    }
  }
  #pragma unroll
  for (int u=0; u<8; ++u) part[ks][u][lane] = acc[u];
  __syncthreads();
  if (!valid) return;

  for (int idx=tid; idx<8*BB; idx+=256){
    int u = idx>>6, b = idx&63;
    int c = c0+u;
    float v = part[0][u][b] + part[1][u][b] + part[2][u][b] + part[3][u][b];
    if (isout){
      out[((size_t)b*TT + t)*DBX + c] = sigmf(v + bout[c]);
    } else {
      int u2 = c - DBX;
      int hh = u2 / PPH;
      int p  = u2 - hh*PPH;
      v += bupd[u2];
      if (p < MMM)            kvec_t[b*HS + p*NH + hh] = v;
      else if (p == MMM)      beta[b*NH+hh] = softplusf(v);
      else if (p == MMM+1)    gbuf[b*NH+hh] = sigmf(v);
      else if (p <  MMM+5)    shraw[(b*NH+hh)*3 + (p-(MMM+2))] = v;
      else if (p == MMM+5)    gam[b*NH+hh] = 1.0f + softplusf(v);
      else if (p <  2*MMM+6)  erase[b*HS + hh*MMM + (p-(MMM+6))] = sigmf(v);
      else                    addb[b*HS + hh*MMM + (p-(2*MMM+6))] = tanhf(v);
    }
  }
}

__global__ __launch_bounds__(512) void k_dotsP(
    const float* __restrict__ mem, const float* __restrict__ kvec_t,
    float* __restrict__ dpart, float* __restrict__ n2part)
{
  int b = blockIdx.x, s = blockIdx.y, z = blockIdx.z, tid = threadIdx.x;
  __shared__ __align__(16) float klt[128];
  if (tid < 128) klt[tid] = kvec_t[b*HS + z*128 + tid];
  __syncthreads();
  int a = s*512 + tid;
  const float* mp = mem + (size_t)b*MMM*AAA + (size_t)(z*32)*AAA + a;
  const float4* k4 = (const float4*)klt;
  float a0=0,a1=0,a2=0,a3=0,n2=0;
  #pragma unroll 8
  for (int m=0; m<32; ++m){
    float mv = mp[(size_t)m*AAA];
    float4 kv = k4[m];
    a0 += kv.x*mv; a1 += kv.y*mv; a2 += kv.z*mv; a3 += kv.w*mv;
    n2 += mv*mv;
  }
  size_t base = ((size_t)(z*BB+b)*NH)*AAA + a;
  dpart[base]        = a0;
  dpart[base+AAA]    = a1;
  dpart[base+2*AAA]  = a2;
  dpart[base+3*AAA]  = a3;
  n2part[(size_t)(z*BB+b)*AAA + a] = n2;
}

__global__ __launch_bounds__(512) void k_dotsF(
    const float* __restrict__ dpart, const float* __restrict__ n2part,
    const float* __restrict__ kvec_t, const float* __restrict__ beta,
    float* __restrict__ ebuf, float* __restrict__ wcsum)
{
  int b = blockIdx.x, s = blockIdx.y, tid = threadIdx.x;
  __shared__ float red[HS];
  __shared__ float kn[NH];
  __shared__ float rsum[8*NH];
  float kv = kvec_t[b*HS + tid];
  red[tid] = kv*kv;
  __syncthreads();
  #pragma unroll
  for (int off=256; off>=4; off>>=1){
    if (tid < off) red[tid] += red[tid+off];
    __syncthreads();
  }
  if (tid < NH) kn[tid] = sqrtf(red[tid]);
  __syncthreads();

  int a = s*512 + tid;
  float d[NH] = {0,0,0,0};
  float n2 = 0.0f;
  #pragma unroll
  for (int z=0; z<4; ++z){
    size_t base = ((size_t)(z*BB+b)*NH)*AAA + a;
    d[0] += dpart[base];
    d[1] += dpart[base+AAA];
    d[2] += dpart[base+2*AAA];
    d[3] += dpart[base+3*AAA];
    n2   += n2part[(size_t)(z*BB+b)*AAA + a];
  }
  float mn = sqrtf(n2);
  int wid = tid >> 6, lane = tid & 63;
  #pragma unroll
  for (int hh=0; hh<NH; ++hh){
    float sim = d[hh]/(kn[hh]*mn + EPSF);
    float e = expf(beta[b*NH+hh]*sim);
    ebuf[((size_t)(b*NH+hh))*AAA + a] = e;
    float v = e;
    #pragma unroll
    for (int off=32; off>0; off>>=1) v += __shfl_xor(v, off);
    if (lane==0) rsum[wid*NH+hh] = v;
  }
  __syncthreads();
  if (tid < NH){
    float s2 = 0.0f;
    #pragma unroll
    for (int w=0; w<8; ++w) s2 += rsum[w*NH+tid];
    atomicAdd(&wcsum[b*NH+tid], s2);
  }
}

__global__ __launch_bounds__(512) void k_shift(
    const float* __restrict__ ebuf, const float* __restrict__ wcsum,
    const float* __restrict__ gbuf, const float* __restrict__ shraw,
    const float* __restrict__ gam, const float* __restrict__ wt,
    float* __restrict__ wpb, float* __restrict__ wpsum)
{
  int b = blockIdx.x, s = blockIdx.y, tid = threadIdx.x;
  int a = s*512 + tid;
  int am1 = (a + AAA - 1) & (AAA-1);
  int ap1 = (a + 1) & (AAA-1);
  __shared__ float sh[NH*3], gl[NH], gml[NH], winv[NH];
  __shared__ float rsum[8*NH];
  if (tid < NH){
    int hh = tid;
    float s0=shraw[(b*NH+hh)*3], s1=shraw[(b*NH+hh)*3+1], s2=shraw[(b*NH+hh)*3+2];
    float mx = fmaxf(s0, fmaxf(s1, s2));
    float e0=expf(s0-mx), e1=expf(s1-mx), e2=expf(s2-mx);
    float inv = 1.0f/(e0+e1+e2);
    sh[hh*3+0]=e0*inv; sh[hh*3+1]=e1*inv; sh[hh*3+2]=e2*inv;
    gl[hh]  = gbuf[b*NH+hh];
    gml[hh] = gam[b*NH+hh];
    winv[hh]= 1.0f/wcsum[b*NH+hh];
  }
  __syncthreads();
  int wid = tid >> 6, lane = tid & 63;
  #pragma unroll
  for (int hh=0; hh<NH; ++hh){
    const float* eb = ebuf + ((size_t)(b*NH+hh))*AAA;
    const float* wb = wt   + ((size_t)(b*NH+hh))*AAA;
    float inv = winv[hh], g = gl[hh];
    float s0 = sh[hh*3+0], s1 = sh[hh*3+1], s2 = sh[hh*3+2];
    float wgm1 = g*eb[am1]*inv + (1.0f-g)*wb[am1];
    float wg0  = g*eb[a]  *inv + (1.0f-g)*wb[a];
    float wgp1 = g*eb[ap1]*inv + (1.0f-g)*wb[ap1];
    float ws = s0*wgp1 + s1*wg0 + s2*wgm1;
    float wp = powf(ws + EPSF, gml[hh]);
    wpb[((size_t)(b*NH+hh))*AAA + a] = wp;
    float v = wp;
    #pragma unroll
    for (int off=32; off>0; off>>=1) v += __shfl_xor(v, off);
    if (lane==0) rsum[wid*NH+hh] = v;
  }
  __syncthreads();
  if (tid < NH){
    float s3 = 0.0f;
    #pragma unroll
    for (int w=0; w<8; ++w) s3 += rsum[w*NH+tid];
    atomicAdd(&wpsum[b*NH+tid], s3);
  }
}

__global__ __launch_bounds__(512) void k_updA(
    float* __restrict__ mem, const float* __restrict__ wpb, const float* __restrict__ wpsum,
    const float* __restrict__ erase, const float* __restrict__ addb,
    float* __restrict__ wt)
{
  int b = blockIdx.x, s = blockIdx.y, z = blockIdx.z, tid = threadIdx.x;
  int a = s*512 + tid;
  __shared__ __align__(16) float ert[128];
  __shared__ __align__(16) float adt[128];
  if (tid < 128){
    int m = tid >> 2, hh = tid & 3;
    ert[tid] = erase[b*HS + hh*MMM + z*32 + m];
    adt[tid] = addb [b*HS + hh*MMM + z*32 + m];
  }
  float wtn[NH];
  #pragma unroll
  for (int hh=0; hh<NH; ++hh){
    float w = wpb[((size_t)(b*NH+hh))*AAA + a] / wpsum[b*NH+hh];
    wtn[hh] = w;
    if (z == 0) wt[((size_t)(b*NH+hh))*AAA + a] = w;
  }
  __syncthreads();

  float* mp = mem + (size_t)b*MMM*AAA + (size_t)(z*32)*AAA + a;
  const float4* e4 = (const float4*)ert;
  const float4* a4 = (const float4*)adt;
  #pragma unroll 8
  for (int m=0; m<32; ++m){
    float mv = mp[(size_t)m*AAA];
    float4 ev = e4[m], av = a4[m];
    float et = (1.0f - ev.x*wtn[0]) * (1.0f - ev.y*wtn[1])
             * (1.0f - ev.z*wtn[2]) * (1.0f - ev.w*wtn[3]);
    float at = av.x*wtn[0] + av.y*wtn[1] + av.z*wtn[2] + av.w*wtn[3];
    mp[(size_t)m*AAA] = mv*et + at;
  }
}

__global__ __launch_bounds__(512) void k_updB(
    const float* __restrict__ mem, const float* __restrict__ wt,
    float* __restrict__ readTn)
{
  int b = blockIdx.x, my = blockIdx.y, tid = threadIdx.x;
  int wave = tid >> 6, lane = tid & 63;
  int m0 = my*8 + wave;
  int m1 = m0 + 64;
  const float* row0 = mem + (size_t)b*MMM*AAA + (size_t)m0*AAA;
  const float* row1 = mem + (size_t)b*MMM*AAA + (size_t)m1*AAA;
  const float* w0 = wt + ((size_t)(b*NH+0))*AAA;
  const float* w1 = wt + ((size_t)(b*NH+1))*AAA;
  const float* w2 = wt + ((size_t)(b*NH+2))*AAA;
  const float* w3 = wt + ((size_t)(b*NH+3))*AAA;
  float r00=0,r01=0,r02=0,r03=0, r10=0,r11=0,r12=0,r13=0;
  #pragma unroll 4
  for (int it=0; it<32; ++it){
    int a = it*64 + lane;
    float mv0 = row0[a], mv1 = row1[a];
    float wv0 = w0[a], wv1 = w1[a], wv2 = w2[a], wv3 = w3[a];
    r00 += mv0*wv0; r01 += mv0*wv1; r02 += mv0*wv2; r03 += mv0*wv3;
    r10 += mv1*wv0; r11 += mv1*wv1; r12 += mv1*wv2; r13 += mv1*wv3;
  }
  float rr[2][NH] = {{r00,r01,r02,r03},{r10,r11,r12,r13}};
  #pragma unroll
  for (int q=0; q<2; ++q){
    #pragma unroll
    for (int hh=0; hh<NH; ++hh){
      float v = rr[q][hh];
      #pragma unroll
      for (int off=32; off>0; off>>=1) v += __shfl_xor(v, off);
      rr[q][hh] = v;
    }
  }
  if (lane == 0){
    #pragma unroll
    for (int hh=0; hh<NH; ++hh){
      readTn[(size_t)(hh*MMM+m0)*BB + b] = rr[0][hh];
      readTn[(size_t)(hh*MMM+m1)*BB + b] = rr[1][hh];
    }
  }
}

extern "C" void kernel_launch(void* const* d_in, const int* in_sizes, int n_in,
                              void* d_out, int out_size, void* d_ws, size_t ws_size,
                              hipStream_t stream){
  const float* x    = (const float*)d_in[0];
  const float* Wst  = (const float*)d_in[1];
  const float* bst  = (const float*)d_in[2];
  const float* Wout = (const float*)d_in[3];
  const float* bout = (const float*)d_in[4];
  const float* Wupd = (const float*)d_in[5];
  const float* bupd = (const float*)d_in[6];
  float* out = (float*)d_out;

  float* p = (float*)d_ws;
  float* xT     = p; p += (size_t)TT*IND*BB;  // 8.65 MB
  float* hT     = p; p += 2*HS*BB;
  float* readT  = p; p += 2*HS*BB;
  float* hpart  = p; p += KSPL*HS*BB;
  float* kvec_t = p; p += BB*HS;
  float* beta   = p; p += BB*NH;
  float* gbuf   = p; p += BB*NH;
  float* gam    = p; p += BB*NH;
  float* shraw  = p; p += BB*NH*3;
  float* erase  = p; p += BB*HS;
  float* addb   = p; p += BB*HS;
  float* wcsum  = p; p += BB*NH;
  float* wpsum  = p; p += BB*NH;
  float* haloL  = p; p += 1024*8;
  float* haloR  = p; p += 1024*8;
  float* wt     = p; p += BB*NH*AAA;
  float* mem    = p; p += (size_t)BB*MMM*AAA;
  float* ebuf   = p; p += BB*NH*AAA;
  float* wpb    = p; p += 4*(size_t)BB*NH*AAA;
  float* n2part = p; p += 4*BB*AAA;
  float* dpart  = wpb;

  k_tx<<<BB, 256, 0, stream>>>(x, xT);

  void* args[] = { (void*)&xT, (void*)&Wst, (void*)&bst, (void*)&Wout, (void*)&bout,
                   (void*)&Wupd, (void*)&bupd, (void*)&out, (void*)&hT, (void*)&readT,
                   (void*)&hpart, (void*)&kvec_t, (void*)&beta, (void*)&gbuf, (void*)&gam,
                   (void*)&shraw, (void*)&erase, (void*)&addb, (void*)&wcsum, (void*)&wpsum,
                   (void*)&haloL, (void*)&haloR };
  hipError_t err = hipLaunchCooperativeKernel((void*)k_persist, dim3(256), dim3(512),
                                              args, 0, stream);
  if (err != hipSuccess){
    // -------- fallback: round-6 verified multi-kernel pipeline --------
    k_init<<<2048, 256, 0, stream>>>(hT, readT, wt, mem);
    for (int t=0; t<TT; ++t){
      const float* hTp = hT    + (t&1)*HS*BB;
      float* hTn       = hT    + ((t+1)&1)*HS*BB;
      const float* rTp = readT + (t&1)*HS*BB;
      float* rTn       = readT + ((t+1)&1)*HS*BB;
      k1_state<<<dim3(32,KSPL), 256, 0, stream>>>(xT, Wst, hTp, rTp, hpart, wcsum, wpsum, t);
      k2h<<<64, 512, 0, stream>>>(hpart, bst, hTn);
      k2_outupd<<<dim3(259), 256, 0, stream>>>(hTn, Wout, bout, Wupd, bupd, out,
          kvec_t, beta, gbuf, gam, shraw, erase, addb, t);
      k_dotsP<<<dim3(BB,4,4), 512, 0, stream>>>(mem, kvec_t, dpart, n2part);
      k_dotsF<<<dim3(BB,4), 512, 0, stream>>>(dpart, n2part, kvec_t, beta, ebuf, wcsum);
      k_shift<<<dim3(BB,4), 512, 0, stream>>>(ebuf, wcsum, gbuf, shraw, gam, wt, wpb, wpsum);
      k_updA<<<dim3(BB,4,4), 512, 0, stream>>>(mem, wpb, wpsum, erase, addb, wt);
      k_updB<<<dim3(BB,8), 512, 0, stream>>>(mem, wt, rTn);
    }
  }
}

// Round 12
// 114197.131 us; speedup vs baseline: 1.0795x; 1.0795x over previous
//
#include <hip/hip_runtime.h>
#include <hip/hip_cooperative_groups.h>
#include <math.h>

namespace cg = cooperative_groups;

#define BB 64
#define TT 128
#define DBX 256
#define IND 264
#define HS 512
#define NH 4
#define MMM 128
#define AAA 2048
#define PPH 390
#define NCOLS 2072
#define KSPL 8
#define KCH  161
#define EPSF 1e-8f

__device__ __forceinline__ float sigmf(float x){ return 1.0f/(1.0f+expf(-x)); }
__device__ __forceinline__ float softplusf(float x){ return (x > 20.0f) ? x : log1pf(expf(x)); }
__device__ __forceinline__ float wred64(float v){
  #pragma unroll
  for (int off=32; off>0; off>>=1) v += __shfl_xor(v, off);
  return v;
}

// ---------------- transpose x[b][t][i] -> xT[t*IND+i][b] (once) ----------------
__global__ __launch_bounds__(256) void k_tx(const float* __restrict__ x, float* __restrict__ xT){
  int b = blockIdx.x;
  for (int f = threadIdx.x; f < TT*IND; f += 256)
    xT[(size_t)f*BB + b] = x[(size_t)b*TT*IND + f];
}

// ================= persistent cooperative kernel (mem STREAMED from global) =================
// 256 blocks x 512 threads, 1 block/CU. block = (b, q): b = bid>>2, q = bid&3.
// Thread owns col = q*512+tid of mem[b][:][col]; mem streamed (L3-resident), wt in registers.
__global__ __launch_bounds__(512) void k_persist(
    const float* __restrict__ xT, const float* __restrict__ Wst, const float* __restrict__ bst,
    const float* __restrict__ Wout, const float* __restrict__ bout,
    const float* __restrict__ Wupd, const float* __restrict__ bupd,
    float* __restrict__ out, float* __restrict__ memG,
    float* __restrict__ hT, float* __restrict__ readT, float* __restrict__ hpart,
    float* __restrict__ kvec_t, float* __restrict__ beta, float* __restrict__ gbuf,
    float* __restrict__ gam, float* __restrict__ shraw,
    float* __restrict__ erase, float* __restrict__ addb,
    float* __restrict__ wcsum, float* __restrict__ wpsum,
    float* __restrict__ haloL, float* __restrict__ haloR)
{
  cg::grid_group grid = cg::this_grid();
  __shared__ float sm[11584];   // 46.3 KB static (P6 peak)
  const int bid = blockIdx.x, tid = threadIdx.x;
  const int b = bid >> 2, q = bid & 3;
  const int col = q*512 + tid;
  const int lane = tid & 63, wave = tid >> 6;   // 8 waves

  // init this block's mem slice (own cols only; no cross-block access anywhere)
  {
    float* mp = memG + (size_t)b*MMM*AAA + col;
    for (int m=0; m<128; ++m) mp[(size_t)m*AAA] = 0.01f;
  }
  float wt[4];
  #pragma unroll
  for (int h=0;h<4;++h) wt[h] = (col==0)?1.0f:0.0f;
  float e_r[4], wp_r[4];

  // P1: 2048 tasks (512 j x 4 kq) over 2048 waves -> 1 task/wave
  const int task1 = bid*8 + wave;
  const int j1 = task1 >> 2, kq1 = task1 & 3, k01 = kq1*322;
  // P3: 2072 cols over 2048 waves: col w3, plus w3<24 also col 2048+w3
  const int w3 = bid*8 + wave;

  for (int t=0; t<TT; ++t){
    // ======== P1: controller state GEMV partial (+zero wcsum/wpsum) ========
    {
      if (bid == 0 && tid < 256) wcsum[tid] = 0.0f;
      if (bid == 1 && tid < 256) wpsum[tid] = 0.0f;
      const float* xt  = xT + (size_t)t*IND*BB;
      const float* hTp = hT + ((t+1)&1)*HS*BB;
      const float* rTp = readT + (t&1)*HS*BB;
      const int kend = k01 + 322;
      float a0 = 0.0f;
      { int s_ = k01, e_ = kend < IND ? kend : IND;
        #pragma unroll 4
        for (int k=s_; k<e_; ++k) a0 += xt[k*BB+lane]*Wst[(size_t)k*HS + j1]; }
      { int s_ = k01 > IND ? k01 : IND, e_ = kend < (IND+HS) ? kend : (IND+HS);
        if (t == 0){
          #pragma unroll 4
          for (int k=s_; k<e_; ++k) a0 += Wst[(size_t)k*HS + j1];          // h0 = 1
        } else {
          #pragma unroll 4
          for (int k=s_; k<e_; ++k) a0 += hTp[(k-IND)*BB+lane]*Wst[(size_t)k*HS + j1];
        } }
      { int s_ = k01 > (IND+HS) ? k01 : (IND+HS);
        if (t == 0){
          #pragma unroll 4
          for (int k=s_; k<kend; ++k) a0 += 0.01f*Wst[(size_t)k*HS + j1];  // read0 = 0.01
        } else {
          #pragma unroll 4
          for (int k=s_; k<kend; ++k) a0 += rTp[(k-IND-HS)*BB+lane]*Wst[(size_t)k*HS + j1];
        } }
      hpart[(size_t)kq1*HS*BB + j1*BB + lane] = a0;
    }
    grid.sync();

    // ======== P2: h finalize + zero next read accumulator ========
    {
      int gid = bid*512 + tid;    // 0..131071
      if (gid < HS*BB){
        float v = hpart[gid] + hpart[HS*BB+gid] + hpart[2*HS*BB+gid] + hpart[3*HS*BB+gid];
        hT[(t&1)*HS*BB + gid] = sigmf(v + bst[gid>>6]);
      } else if (gid < 2*HS*BB){
        readT[((t+1)&1)*HS*BB + (gid - HS*BB)] = 0.0f;
      }
    }
    grid.sync();

    // ======== P3: out/upd GEMV + per-head transforms ========
    {
      const float* hc = hT + (t&1)*HS*BB;
      #pragma unroll
      for (int rep=0; rep<2; ++rep){
        int c = (rep==0) ? w3 : 2048 + w3;
        if (rep==1 && w3 >= NCOLS-2048) break;
        const float* wcol; int strd; float v;
        if (c < DBX){ wcol = Wout + c; strd = DBX; v = bout[c]; }
        else        { wcol = Wupd + (c-DBX); strd = NH*PPH; v = bupd[c-DBX]; }
        #pragma unroll 8
        for (int k=0; k<HS; ++k) v += hc[k*BB+lane]*wcol[(size_t)k*strd];
        if (c < DBX){
          out[((size_t)lane*TT + t)*DBX + c] = sigmf(v);
        } else {
          int u2 = c - DBX; int hh = u2/PPH; int p = u2 - hh*PPH;
          if (p < MMM)            kvec_t[lane*HS + p*NH + hh] = v;
          else if (p == MMM)      beta[lane*NH+hh] = softplusf(v);
          else if (p == MMM+1)    gbuf[lane*NH+hh] = sigmf(v);
          else if (p <  MMM+5)    shraw[(lane*NH+hh)*3 + (p-(MMM+2))] = v;
          else if (p == MMM+5)    gam[lane*NH+hh] = 1.0f + softplusf(v);
          else if (p <  2*MMM+6)  erase[lane*HS + hh*MMM + (p-(MMM+6))] = sigmf(v);
          else                    addb[lane*HS + hh*MMM + (p-(2*MMM+6))] = tanhf(v);
        }
      }
    }
    grid.sync();

    // ======== P4: content dots (streamed mem) + e + wcsum + halo ========
    {
      float* kl  = sm;         // [512] layout [m*4+h]
      float* red = sm + 512;   // [512]
      float* pb  = sm + 1024;  // [4]
      float* knl = sm + 1028;  // [4]
      float* wsr = sm + 1032;  // [32]
      kl[tid] = kvec_t[b*HS + tid];
      if (tid < 4) pb[tid] = beta[b*NH + tid];
      __syncthreads();
      red[tid] = kl[tid]*kl[tid];
      __syncthreads();
      for (int off=256; off>=4; off>>=1){
        if (tid < off) red[tid] += red[tid+off];
        __syncthreads();
      }
      if (tid < 4) knl[tid] = sqrtf(red[tid]);
      __syncthreads();
      const float4* kl4 = (const float4*)kl;
      const float* mp = memG + (size_t)b*MMM*AAA + col;
      float d0=0,d1=0,d2=0,d3=0,n2=0;
      for (int mb=0; mb<128; mb+=16){
        float mv[16];
        #pragma unroll
        for (int u=0;u<16;++u) mv[u] = mp[(size_t)(mb+u)*AAA];
        #pragma unroll
        for (int u=0;u<16;++u){
          float4 kv = kl4[mb+u];
          d0 += kv.x*mv[u]; d1 += kv.y*mv[u]; d2 += kv.z*mv[u]; d3 += kv.w*mv[u];
          n2 += mv[u]*mv[u];
        }
      }
      float mn = sqrtf(n2);
      float dd[4] = {d0,d1,d2,d3};
      #pragma unroll
      for (int h=0; h<4; ++h)
        e_r[h] = expf(pb[h] * (dd[h]/(knl[h]*mn + EPSF)));
      #pragma unroll
      for (int h=0; h<4; ++h){
        float v = wred64(e_r[h]);
        if (lane == 0) wsr[wave*4+h] = v;
      }
      __syncthreads();
      if (tid < 4){
        float s2 = 0.0f;
        #pragma unroll
        for (int w=0; w<8; ++w) s2 += wsr[w*4+tid];
        atomicAdd(&wcsum[b*NH+tid], s2);
      }
      if (tid == 0){
        #pragma unroll
        for (int h=0;h<4;++h){ haloL[bid*8+h] = e_r[h]; haloL[bid*8+4+h] = wt[h]; }
      }
      if (tid == 511){
        #pragma unroll
        for (int h=0;h<4;++h){ haloR[bid*8+h] = e_r[h]; haloR[bid*8+4+h] = wt[h]; }
      }
    }
    grid.sync();

    // ======== P5: normalize + interpolate + shift + sharpen + wpsum ========
    {
      float (*ew)[9] = (float(*)[9])sm;    // [512][9] = 4608
      float* sh  = sm + 4608;  // [12]
      float* gg  = sm + 4620;  // [4]
      float* gm  = sm + 4624;  // [4]
      float* wci = sm + 4628;  // [4]
      float* wsr = sm + 4632;  // [32]
      #pragma unroll
      for (int h=0;h<4;++h){ ew[tid][h] = e_r[h]; ew[tid][4+h] = wt[h]; }
      if (tid < 4){
        gg[tid] = gbuf[b*NH+tid];
        gm[tid] = gam[b*NH+tid];
        wci[tid] = 1.0f/wcsum[b*NH+tid];
        float s0 = shraw[(b*NH+tid)*3], s1 = shraw[(b*NH+tid)*3+1], s2 = shraw[(b*NH+tid)*3+2];
        float mx = fmaxf(s0, fmaxf(s1, s2));
        float e0 = expf(s0-mx), e1 = expf(s1-mx), e2 = expf(s2-mx);
        float inv = 1.0f/(e0+e1+e2);
        sh[tid*3] = e0*inv; sh[tid*3+1] = e1*inv; sh[tid*3+2] = e2*inv;
      }
      __syncthreads();
      #pragma unroll
      for (int h=0; h<4; ++h){
        float eL, wL, eR, wR;
        if (tid == 0){
          const float* hb = haloR + (b*4 + ((q+3)&3))*8;
          eL = hb[h]; wL = hb[4+h];
        } else { eL = ew[tid-1][h]; wL = ew[tid-1][4+h]; }
        if (tid == 511){
          const float* hb = haloL + (b*4 + ((q+1)&3))*8;
          eR = hb[h]; wR = hb[4+h];
        } else { eR = ew[tid+1][h]; wR = ew[tid+1][4+h]; }
        float g = gg[h], inv = wci[h];
        float wg0 = g*e_r[h]*inv + (1.0f-g)*wt[h];
        float wgL = g*eL*inv     + (1.0f-g)*wL;
        float wgR = g*eR*inv     + (1.0f-g)*wR;
        float ws = sh[h*3]*wgR + sh[h*3+1]*wg0 + sh[h*3+2]*wgL;
        wp_r[h] = powf(ws + EPSF, gm[h]);
      }
      #pragma unroll
      for (int h=0; h<4; ++h){
        float v = wred64(wp_r[h]);
        if (lane == 0) wsr[wave*4+h] = v;
      }
      __syncthreads();
      if (tid < 4){
        float s3 = 0.0f;
        #pragma unroll
        for (int w=0; w<8; ++w) s3 += wsr[w*4+tid];
        atomicAdd(&wpsum[b*NH+tid], s3);
      }
    }
    grid.sync();

    // ======== P6: wt_new + mem update (streamed) + read einsum (LDS reduce) ========
    {
      float* erT = sm;          // [512] [m*4+h]
      float* adT = sm + 512;    // [512]
      float* wlT = sm + 1024;   // [4][528] padded per-col weights
      float* M   = sm + 3136;   // [16][528]
      #pragma unroll
      for (int h=0;h<4;++h) wt[h] = wp_r[h] / wpsum[b*NH+h];
      {
        int m0 = tid >> 2, h0 = tid & 3;
        erT[tid] = erase[b*HS + h0*MMM + m0];   // erT[m*4+h]
        adT[tid] = addb [b*HS + h0*MMM + m0];
      }
      const int pa = tid + ((tid>>7)<<2);       // padded col index (pad 4 per 128)
      #pragma unroll
      for (int h=0;h<4;++h) wlT[h*528 + pa] = wt[h];
      __syncthreads();
      const float4* e4 = (const float4*)erT;
      const float4* a4 = (const float4*)adT;
      float* mpw = memG + (size_t)b*MMM*AAA + col;
      float* rT = readT + ((t+1)&1)*HS*BB;
      const int task = tid >> 3, qq = tid & 7;  // 64 tasks: row=task>>2, hh=task&3
      const int row = task >> 2, hh = task & 3;
      const int cs = qq*64 + ((qq>>1)<<2);      // padded chunk start (64 data cols)
      for (int st=0; st<8; ++st){
        float mv[16];
        #pragma unroll
        for (int r=0;r<16;++r) mv[r] = mpw[(size_t)(st*16+r)*AAA];
        #pragma unroll
        for (int r=0;r<16;++r){
          float4 ev = e4[st*16+r], av = a4[st*16+r];
          float et = (1.0f - ev.x*wt[0])*(1.0f - ev.y*wt[1])
                   * (1.0f - ev.z*wt[2])*(1.0f - ev.w*wt[3]);
          float at = av.x*wt[0] + av.y*wt[1] + av.z*wt[2] + av.w*wt[3];
          mv[r] = mv[r]*et + at;
        }
        #pragma unroll
        for (int r=0;r<16;++r) mpw[(size_t)(st*16+r)*AAA] = mv[r];
        __syncthreads();            // protect M from previous stage's readers
        #pragma unroll
        for (int r=0;r<16;++r) M[r*528 + pa] = mv[r];
        __syncthreads();
        float acc = 0.0f;
        #pragma unroll
        for (int j4=0; j4<16; ++j4){
          float4 m4 = *(const float4*)&M[row*528 + cs + j4*4];
          float4 w4 = *(const float4*)&wlT[hh*528 + cs + j4*4];
          acc += m4.x*w4.x + m4.y*w4.y + m4.z*w4.z + m4.w*w4.w;
        }
        acc += __shfl_xor(acc, 1);
        acc += __shfl_xor(acc, 2);
        acc += __shfl_xor(acc, 4);
        if (qq == 0)
          atomicAdd(&rT[(hh*MMM + st*16 + row)*BB + b], acc);
      }
    }
    grid.sync();
  }
}

// ================= fallback: round-6 verified pipeline =================
__global__ void k_init(float* __restrict__ hT, float* __restrict__ readT,
                       float* __restrict__ wt, float* __restrict__ mem){
  int i = blockIdx.x*blockDim.x + threadIdx.x;
  int stride = gridDim.x*blockDim.x;
  for (int idx=i; idx<BB*MMM*AAA; idx+=stride) mem[idx]=0.01f;
  for (int idx=i; idx<HS*BB; idx+=stride){ hT[idx]=1.0f; readT[idx]=0.01f; }
  for (int idx=i; idx<BB*NH*AAA; idx+=stride) wt[idx] = ((idx & (AAA-1))==0)?1.0f:0.0f;
}

__global__ __launch_bounds__(256) void k1_state(
    const float* __restrict__ xT, const float* __restrict__ Wst,
    const float* __restrict__ hTp, const float* __restrict__ readTp,
    float* __restrict__ hpart, float* __restrict__ wcsum, float* __restrict__ wpsum, int t)
{
  int tid = threadIdx.x, wave = tid>>6, lane = tid&63;
  int ks = blockIdx.y;
  int j0 = blockIdx.x*16 + wave*4;
  if (blockIdx.x==0 && ks==0){
    wcsum[tid] = 0.0f;
    wpsum[tid] = 0.0f;
  }
  float a0=0,a1=0,a2=0,a3=0;
  int k0 = ks*KCH, kend = k0+KCH;

  #define K1STEP(AEXPR) { float aV=(AEXPR); \
      float4 wv = *(const float4*)(Wst + (size_t)k*HS + j0); \
      a0 += aV*wv.x; a1 += aV*wv.y; a2 += aV*wv.z; a3 += aV*wv.w; }

  {int s = k0, e = kend<IND?kend:IND;
   #pragma unroll 4
   for (int k=s;k<e;++k) K1STEP(xT[((size_t)t*IND + k)*BB + lane]); }
  {int s = k0>IND?k0:IND, e = kend<(IND+HS)?kend:(IND+HS);
   #pragma unroll 4
   for (int k=s;k<e;++k) K1STEP(hTp[(k-IND)*BB + lane]); }
  {int s = k0>(IND+HS)?k0:(IND+HS), e = kend;
   #pragma unroll 4
   for (int k=s;k<e;++k) K1STEP(readTp[(k-IND-HS)*BB + lane]); }
  #undef K1STEP

  float* hp = hpart + (size_t)ks*HS*BB + (size_t)j0*BB + lane;
  hp[0]    = a0;
  hp[BB]   = a1;
  hp[2*BB] = a2;
  hp[3*BB] = a3;
}

__global__ __launch_bounds__(512) void k2h(
    const float* __restrict__ hpart, const float* __restrict__ bst, float* __restrict__ hTn)
{
  int idx = blockIdx.x*512 + threadIdx.x;
  float v = 0.0f;
  #pragma unroll
  for (int ks=0; ks<KSPL; ++ks) v += hpart[(size_t)ks*HS*BB + idx];
  hTn[idx] = sigmf(v + bst[idx>>6]);
}

__global__ __launch_bounds__(256) void k2_outupd(
    const float* __restrict__ hTn,
    const float* __restrict__ Wout, const float* __restrict__ bout,
    const float* __restrict__ Wupd, const float* __restrict__ bupd,
    float* __restrict__ out,
    float* __restrict__ kvec_t, float* __restrict__ beta, float* __restrict__ gbuf,
    float* __restrict__ gam, float* __restrict__ shraw,
    float* __restrict__ erase, float* __restrict__ addb, int t)
{
  __shared__ float part[4][8][BB];
  int tid = threadIdx.x, ks = tid>>6, lane = tid&63;
  int c0 = blockIdx.x*8;
  bool isout = (c0 < DBX);
  size_t strd = isout ? (size_t)DBX : (size_t)(NH*PPH);
  const float* wbase = isout ? (Wout + c0) : (Wupd + (c0 - DBX));
  bool valid = (c0 < NCOLS);

  float acc[8] = {0,0,0,0,0,0,0,0};
  if (valid){
    int k0 = ks*128;
    #pragma unroll 4
    for (int k=k0; k<k0+128; ++k){
      float a = hTn[k*BB + lane];
      const float4* w4 = (const float4*)(wbase + (size_t)k*strd);
      float4 wa = w4[0], wb = w4[1];
      acc[0]+=a*wa.x; acc[1]+=a*wa.y; acc[2]+=a*wa.z; acc[3]+=a*wa.w;
      acc[4]+=a*wb.x; acc[5]+=a*wb.y; acc[6]+=a*wb.z; acc[7]+=a*wb.w;
    }
  }
  #pragma unroll
  for (int u=0; u<8; ++u) part[ks][u][lane] = acc[u];
  __syncthreads();
  if (!valid) return;

  for (int idx=tid; idx<8*BB; idx+=256){
    int u = idx>>6, bb = idx&63;
    int c = c0+u;
    float v = part[0][u][bb] + part[1][u][bb] + part[2][u][bb] + part[3][u][bb];
    if (isout){
      out[((size_t)bb*TT + t)*DBX + c] = sigmf(v + bout[c]);
    } else {
      int u2 = c - DBX;
      int hh = u2 / PPH;
      int p  = u2 - hh*PPH;
      v += bupd[u2];
      if (p < MMM)            kvec_t[bb*HS + p*NH + hh] = v;
      else if (p == MMM)      beta[bb*NH+hh] = softplusf(v);
      else if (p == MMM+1)    gbuf[bb*NH+hh] = sigmf(v);
      else if (p <  MMM+5)    shraw[(bb*NH+hh)*3 + (p-(MMM+2))] = v;
      else if (p == MMM+5)    gam[bb*NH+hh] = 1.0f + softplusf(v);
      else if (p <  2*MMM+6)  erase[bb*HS + hh*MMM + (p-(MMM+6))] = sigmf(v);
      else                    addb[bb*HS + hh*MMM + (p-(2*MMM+6))] = tanhf(v);
    }
  }
}

__global__ __launch_bounds__(512) void k_dotsP(
    const float* __restrict__ mem, const float* __restrict__ kvec_t,
    float* __restrict__ dpart, float* __restrict__ n2part)
{
  int b = blockIdx.x, s = blockIdx.y, z = blockIdx.z, tid = threadIdx.x;
  __shared__ __align__(16) float klt[128];
  if (tid < 128) klt[tid] = kvec_t[b*HS + z*128 + tid];
  __syncthreads();
  int a = s*512 + tid;
  const float* mp = mem + (size_t)b*MMM*AAA + (size_t)(z*32)*AAA + a;
  const float4* k4 = (const float4*)klt;
  float a0=0,a1=0,a2=0,a3=0,n2=0;
  #pragma unroll 8
  for (int m=0; m<32; ++m){
    float mv = mp[(size_t)m*AAA];
    float4 kv = k4[m];
    a0 += kv.x*mv; a1 += kv.y*mv; a2 += kv.z*mv; a3 += kv.w*mv;
    n2 += mv*mv;
  }
  size_t base = ((size_t)(z*BB+b)*NH)*AAA + a;
  dpart[base]        = a0;
  dpart[base+AAA]    = a1;
  dpart[base+2*AAA]  = a2;
  dpart[base+3*AAA]  = a3;
  n2part[(size_t)(z*BB+b)*AAA + a] = n2;
}

__global__ __launch_bounds__(512) void k_dotsF(
    const float* __restrict__ dpart, const float* __restrict__ n2part,
    const float* __restrict__ kvec_t, const float* __restrict__ beta,
    float* __restrict__ ebuf, float* __restrict__ wcsum)
{
  int b = blockIdx.x, s = blockIdx.y, tid = threadIdx.x;
  __shared__ float red[HS];
  __shared__ float kn[NH];
  __shared__ float rsum[8*NH];
  float kv = kvec_t[b*HS + tid];
  red[tid] = kv*kv;
  __syncthreads();
  #pragma unroll
  for (int off=256; off>=4; off>>=1){
    if (tid < off) red[tid] += red[tid+off];
    __syncthreads();
  }
  if (tid < NH) kn[tid] = sqrtf(red[tid]);
  __syncthreads();

  int a = s*512 + tid;
  float d[NH] = {0,0,0,0};
  float n2 = 0.0f;
  #pragma unroll
  for (int z=0; z<4; ++z){
    size_t base = ((size_t)(z*BB+b)*NH)*AAA + a;
    d[0] += dpart[base];
    d[1] += dpart[base+AAA];
    d[2] += dpart[base+2*AAA];
    d[3] += dpart[base+3*AAA];
    n2   += n2part[(size_t)(z*BB+b)*AAA + a];
  }
  float mn = sqrtf(n2);
  int wid = tid >> 6, lane = tid & 63;
  #pragma unroll
  for (int hh=0; hh<NH; ++hh){
    float sim = d[hh]/(kn[hh]*mn + EPSF);
    float e = expf(beta[b*NH+hh]*sim);
    ebuf[((size_t)(b*NH+hh))*AAA + a] = e;
    float v = e;
    #pragma unroll
    for (int off=32; off>0; off>>=1) v += __shfl_xor(v, off);
    if (lane==0) rsum[wid*NH+hh] = v;
  }
  __syncthreads();
  if (tid < NH){
    float s2 = 0.0f;
    #pragma unroll
    for (int w=0; w<8; ++w) s2 += rsum[w*NH+tid];
    atomicAdd(&wcsum[b*NH+tid], s2);
  }
}

__global__ __launch_bounds__(512) void k_shift(
    const float* __restrict__ ebuf, const float* __restrict__ wcsum,
    const float* __restrict__ gbuf, const float* __restrict__ shraw,
    const float* __restrict__ gam, const float* __restrict__ wt,
    float* __restrict__ wpb, float* __restrict__ wpsum)
{
  int b = blockIdx.x, s = blockIdx.y, tid = threadIdx.x;
  int a = s*512 + tid;
  int am1 = (a + AAA - 1) & (AAA-1);
  int ap1 = (a + 1) & (AAA-1);
  __shared__ float sh[NH*3], gl[NH], gml[NH], winv[NH];
  __shared__ float rsum[8*NH];
  if (tid < NH){
    int hh = tid;
    float s0=shraw[(b*NH+hh)*3], s1=shraw[(b*NH+hh)*3+1], s2=shraw[(b*NH+hh)*3+2];
    float mx = fmaxf(s0, fmaxf(s1, s2));
    float e0=expf(s0-mx), e1=expf(s1-mx), e2=expf(s2-mx);
    float inv = 1.0f/(e0+e1+e2);
    sh[hh*3+0]=e0*inv; sh[hh*3+1]=e1*inv; sh[hh*3+2]=e2*inv;
    gl[hh]  = gbuf[b*NH+hh];
    gml[hh] = gam[b*NH+hh];
    winv[hh]= 1.0f/wcsum[b*NH+hh];
  }
  __syncthreads();
  int wid = tid >> 6, lane = tid & 63;
  #pragma unroll
  for (int hh=0; hh<NH; ++hh){
    const float* eb = ebuf + ((size_t)(b*NH+hh))*AAA;
    const float* wb = wt   + ((size_t)(b*NH+hh))*AAA;
    float inv = winv[hh], g = gl[hh];
    float s0 = sh[hh*3+0], s1 = sh[hh*3+1], s2 = sh[hh*3+2];
    float wgm1 = g*eb[am1]*inv + (1.0f-g)*wb[am1];
    float wg0  = g*eb[a]  *inv + (1.0f-g)*wb[a];
    float wgp1 = g*eb[ap1]*inv + (1.0f-g)*wb[ap1];
    float ws = s0*wgp1 + s1*wg0 + s2*wgm1;
    float wp = powf(ws + EPSF, gml[hh]);
    wpb[((size_t)(b*NH+hh))*AAA + a] = wp;
    float v = wp;
    #pragma unroll
    for (int off=32; off>0; off>>=1) v += __shfl_xor(v, off);
    if (lane==0) rsum[wid*NH+hh] = v;
  }
  __syncthreads();
  if (tid < NH){
    float s3 = 0.0f;
    #pragma unroll
    for (int w=0; w<8; ++w) s3 += rsum[w*NH+tid];
    atomicAdd(&wpsum[b*NH+tid], s3);
  }
}

__global__ __launch_bounds__(512) void k_updA(
    float* __restrict__ mem, const float* __restrict__ wpb, const float* __restrict__ wpsum,
    const float* __restrict__ erase, const float* __restrict__ addb,
    float* __restrict__ wt)
{
  int b = blockIdx.x, s = blockIdx.y, z = blockIdx.z, tid = threadIdx.x;
  int a = s*512 + tid;
  __shared__ __align__(16) float ert[128];
  __shared__ __align__(16) float adt[128];
  if (tid < 128){
    int m = tid >> 2, hh = tid & 3;
    ert[tid] = erase[b*HS + hh*MMM + z*32 + m];
    adt[tid] = addb [b*HS + hh*MMM + z*32 + m];
  }
  float wtn[NH];
  #pragma unroll
  for (int hh=0; hh<NH; ++hh){
    float w = wpb[((size_t)(b*NH+hh))*AAA + a] / wpsum[b*NH+hh];
    wtn[hh] = w;
    if (z == 0) wt[((size_t)(b*NH+hh))*AAA + a] = w;
  }
  __syncthreads();

  float* mp = mem + (size_t)b*MMM*AAA + (size_t)(z*32)*AAA + a;
  const float4* e4 = (const float4*)ert;
  const float4* a4 = (const float4*)adt;
  #pragma unroll 8
  for (int m=0; m<32; ++m){
    float mv = mp[(size_t)m*AAA];
    float4 ev = e4[m], av = a4[m];
    float et = (1.0f - ev.x*wtn[0]) * (1.0f - ev.y*wtn[1])
             * (1.0f - ev.z*wtn[2]) * (1.0f - ev.w*wtn[3]);
    float at = av.x*wtn[0] + av.y*wtn[1] + av.z*wtn[2] + av.w*wtn[3];
    mp[(size_t)m*AAA] = mv*et + at;
  }
}

__global__ __launch_bounds__(512) void k_updB(
    const float* __restrict__ mem, const float* __restrict__ wt,
    float* __restrict__ readTn)
{
  int b = blockIdx.x, my = blockIdx.y, tid = threadIdx.x;
  int wave = tid >> 6, lane = tid & 63;
  int m0 = my*8 + wave;
  int m1 = m0 + 64;
  const float* row0 = mem + (size_t)b*MMM*AAA + (size_t)m0*AAA;
  const float* row1 = mem + (size_t)b*MMM*AAA + (size_t)m1*AAA;
  const float* w0 = wt + ((size_t)(b*NH+0))*AAA;
  const float* w1 = wt + ((size_t)(b*NH+1))*AAA;
  const float* w2 = wt + ((size_t)(b*NH+2))*AAA;
  const float* w3 = wt + ((size_t)(b*NH+3))*AAA;
  float r00=0,r01=0,r02=0,r03=0, r10=0,r11=0,r12=0,r13=0;
  #pragma unroll 4
  for (int it=0; it<32; ++it){
    int a = it*64 + lane;
    float mv0 = row0[a], mv1 = row1[a];
    float wv0 = w0[a], wv1 = w1[a], wv2 = w2[a], wv3 = w3[a];
    r00 += mv0*wv0; r01 += mv0*wv1; r02 += mv0*wv2; r03 += mv0*wv3;
    r10 += mv1*wv0; r11 += mv1*wv1; r12 += mv1*wv2; r13 += mv1*wv3;
  }
  float rr[2][NH] = {{r00,r01,r02,r03},{r10,r11,r12,r13}};
  #pragma unroll
  for (int q=0; q<2; ++q){
    #pragma unroll
    for (int hh=0; hh<NH; ++hh){
      float v = rr[q][hh];
      #pragma unroll
      for (int off=32; off>0; off>>=1) v += __shfl_xor(v, off);
      rr[q][hh] = v;
    }
  }
  if (lane == 0){
    #pragma unroll
    for (int hh=0; hh<NH; ++hh){
      readTn[(size_t)(hh*MMM+m0)*BB + b] = rr[0][hh];
      readTn[(size_t)(hh*MMM+m1)*BB + b] = rr[1][hh];
    }
  }
}

extern "C" void kernel_launch(void* const* d_in, const int* in_sizes, int n_in,
                              void* d_out, int out_size, void* d_ws, size_t ws_size,
                              hipStream_t stream){
  const float* x    = (const float*)d_in[0];
  const float* Wst  = (const float*)d_in[1];
  const float* bst  = (const float*)d_in[2];
  const float* Wout = (const float*)d_in[3];
  const float* bout = (const float*)d_in[4];
  const float* Wupd = (const float*)d_in[5];
  const float* bupd = (const float*)d_in[6];
  float* out = (float*)d_out;

  float* p = (float*)d_ws;
  float* xT     = p; p += (size_t)TT*IND*BB;  // 8.65 MB
  float* hT     = p; p += 2*HS*BB;
  float* readT  = p; p += 2*HS*BB;
  float* hpart  = p; p += KSPL*HS*BB;
  float* kvec_t = p; p += BB*HS;
  float* beta   = p; p += BB*NH;
  float* gbuf   = p; p += BB*NH;
  float* gam    = p; p += BB*NH;
  float* shraw  = p; p += BB*NH*3;
  float* erase  = p; p += BB*HS;
  float* addb   = p; p += BB*HS;
  float* wcsum  = p; p += BB*NH;
  float* wpsum  = p; p += BB*NH;
  float* haloL  = p; p += 1024*8;
  float* haloR  = p; p += 1024*8;
  float* wt     = p; p += BB*NH*AAA;
  float* mem    = p; p += (size_t)BB*MMM*AAA;
  float* ebuf   = p; p += BB*NH*AAA;
  float* wpb    = p; p += 4*(size_t)BB*NH*AAA;
  float* n2part = p; p += 4*BB*AAA;
  float* dpart  = wpb;

  k_tx<<<BB, 256, 0, stream>>>(x, xT);

  void* args[] = { (void*)&xT, (void*)&Wst, (void*)&bst, (void*)&Wout, (void*)&bout,
                   (void*)&Wupd, (void*)&bupd, (void*)&out, (void*)&mem, (void*)&hT,
                   (void*)&readT, (void*)&hpart, (void*)&kvec_t, (void*)&beta, (void*)&gbuf,
                   (void*)&gam, (void*)&shraw, (void*)&erase, (void*)&addb, (void*)&wcsum,
                   (void*)&wpsum, (void*)&haloL, (void*)&haloR };
  hipError_t err = hipLaunchCooperativeKernel((void*)k_persist, dim3(256), dim3(512),
                                              args, 0, stream);
  if (err != hipSuccess){
    // -------- fallback: round-6 verified multi-kernel pipeline --------
    k_init<<<2048, 256, 0, stream>>>(hT, readT, wt, mem);
    for (int t=0; t<TT; ++t){
      const float* hTp = hT    + (t&1)*HS*BB;
      float* hTn       = hT    + ((t+1)&1)*HS*BB;
      const float* rTp = readT + (t&1)*HS*BB;
      float* rTn       = readT + ((t+1)&1)*HS*BB;
      k1_state<<<dim3(32,KSPL), 256, 0, stream>>>(xT, Wst, hTp, rTp, hpart, wcsum, wpsum, t);
      k2h<<<64, 512, 0, stream>>>(hpart, bst, hTn);
      k2_outupd<<<dim3(259), 256, 0, stream>>>(hTn, Wout, bout, Wupd, bupd, out,
          kvec_t, beta, gbuf, gam, shraw, erase, addb, t);
      k_dotsP<<<dim3(BB,4,4), 512, 0, stream>>>(mem, kvec_t, dpart, n2part);
      k_dotsF<<<dim3(BB,4), 512, 0, stream>>>(dpart, n2part, kvec_t, beta, ebuf, wcsum);
      k_shift<<<dim3(BB,4), 512, 0, stream>>>(ebuf, wcsum, gbuf, shraw, gam, wt, wpb, wpsum);
      k_updA<<<dim3(BB,4,4), 512, 0, stream>>>(mem, wpb, wpsum, erase, addb, wt);
      k_updB<<<dim3(BB,8), 512, 0, stream>>>(mem, wt, rTn);
    }
  }
}

// Round 13
// 11610.206 us; speedup vs baseline: 10.6176x; 9.8359x over previous
//
#include <hip/hip_runtime.h>
#include <math.h>

#define BB 64
#define TT 128
#define DBX 256
#define IND 264
#define HS 512
#define NH 4
#define MMM 128
#define AAA 2048
#define PPH 390
#define NCOLS (DBX + NH*PPH)   // 2072
#define KTOT (IND + HS + HS)   // 1288
#define KSPL 8                 // k1 split-K: 8 x 161
#define KCH  161
#define EPSF 1e-8f

__device__ __forceinline__ float sigmf(float x){ return 1.0f/(1.0f+expf(-x)); }
__device__ __forceinline__ float softplusf(float x){ return (x > 20.0f) ? x : log1pf(expf(x)); }

// ---------------- init ----------------
__global__ void k_init(float* __restrict__ hT, float* __restrict__ readT,
                       float* __restrict__ wt, float* __restrict__ mem){
  int i = blockIdx.x*blockDim.x + threadIdx.x;
  int stride = gridDim.x*blockDim.x;
  for (int idx=i; idx<BB*MMM*AAA; idx+=stride) mem[idx]=0.01f;
  for (int idx=i; idx<HS*BB; idx+=stride){ hT[idx]=1.0f; readT[idx]=0.01f; }
  for (int idx=i; idx<BB*NH*AAA; idx+=stride) wt[idx] = ((idx & (AAA-1))==0)?1.0f:0.0f;
}

// ---------------- transpose x[b][t][i] -> xT[t*IND+i][b] (once) ----------------
__global__ __launch_bounds__(256) void k_tx(const float* __restrict__ x, float* __restrict__ xT){
  int b = blockIdx.x;
  for (int f = threadIdx.x; f < TT*IND; f += 256)
    xT[(size_t)f*BB + b] = x[(size_t)b*TT*IND + f];
}

// ---------------- k1: split-K partial GEMM  hpart[ks][j][b] ----------------
__global__ __launch_bounds__(256) void k1_state(
    const float* __restrict__ xT, const float* __restrict__ Wst,
    const float* __restrict__ hTp, const float* __restrict__ readTp,
    float* __restrict__ hpart, float* __restrict__ wcsum, float* __restrict__ wpsum, int t)
{
  int tid = threadIdx.x, wave = tid>>6, lane = tid&63;
  int ks = blockIdx.y;
  int j0 = blockIdx.x*16 + wave*4;
  if (blockIdx.x==0 && ks==0){
    wcsum[tid] = 0.0f;   // BB*NH == 256
    wpsum[tid] = 0.0f;
  }
  float a0=0,a1=0,a2=0,a3=0;
  int k0 = ks*KCH, kend = k0+KCH;

  #define K1STEP(AEXPR) { float aV=(AEXPR); \
      float4 wv = *(const float4*)(Wst + (size_t)k*HS + j0); \
      a0 += aV*wv.x; a1 += aV*wv.y; a2 += aV*wv.z; a3 += aV*wv.w; }

  {int s = k0, e = kend<IND?kend:IND;
   #pragma unroll 4
   for (int k=s;k<e;++k) K1STEP(xT[((size_t)t*IND + k)*BB + lane]); }
  {int s = k0>IND?k0:IND, e = kend<(IND+HS)?kend:(IND+HS);
   #pragma unroll 4
   for (int k=s;k<e;++k) K1STEP(hTp[(k-IND)*BB + lane]); }
  {int s = k0>(IND+HS)?k0:(IND+HS), e = kend;
   #pragma unroll 4
   for (int k=s;k<e;++k) K1STEP(readTp[(k-IND-HS)*BB + lane]); }
  #undef K1STEP

  float* hp = hpart + (size_t)ks*HS*BB + (size_t)j0*BB + lane;
  hp[0]    = a0;
  hp[BB]   = a1;
  hp[2*BB] = a2;
  hp[3*BB] = a3;
}

// ---------------- k2h: reduce split-K partials -> h = sigmoid(. + b) ----------------
__global__ __launch_bounds__(512) void k2h(
    const float* __restrict__ hpart, const float* __restrict__ bst, float* __restrict__ hTn)
{
  int idx = blockIdx.x*512 + threadIdx.x;   // 64 blocks x 512 = 32768 = HS*BB
  float v = 0.0f;
  #pragma unroll
  for (int ks=0; ks<KSPL; ++ks) v += hpart[(size_t)ks*HS*BB + idx];
  hTn[idx] = sigmf(v + bst[idx>>6]);
}

// ---------------- k2: out/upd GEMM, split-K across 4 waves, + transforms ----------------
__global__ __launch_bounds__(256) void k2_outupd(
    const float* __restrict__ hTn,
    const float* __restrict__ Wout, const float* __restrict__ bout,
    const float* __restrict__ Wupd, const float* __restrict__ bupd,
    float* __restrict__ out,
    float* __restrict__ kvec_t, float* __restrict__ beta, float* __restrict__ gbuf,
    float* __restrict__ gam, float* __restrict__ shraw,
    float* __restrict__ erase, float* __restrict__ addb, int t)
{
  __shared__ float part[4][8][BB];
  int tid = threadIdx.x, ks = tid>>6, lane = tid&63;
  int c0 = blockIdx.x*8;
  bool isout = (c0 < DBX);
  size_t strd = isout ? (size_t)DBX : (size_t)(NH*PPH);
  const float* wbase = isout ? (Wout + c0) : (Wupd + (c0 - DBX));
  bool valid = (c0 < NCOLS);

  float acc[8] = {0,0,0,0,0,0,0,0};
  if (valid){
    int k0 = ks*128;
    #pragma unroll 4
    for (int k=k0; k<k0+128; ++k){
      float a = hTn[k*BB + lane];
      const float4* w4 = (const float4*)(wbase + (size_t)k*strd);
      float4 wa = w4[0], wb = w4[1];
      acc[0]+=a*wa.x; acc[1]+=a*wa.y; acc[2]+=a*wa.z; acc[3]+=a*wa.w;
      acc[4]+=a*wb.x; acc[5]+=a*wb.y; acc[6]+=a*wb.z; acc[7]+=a*wb.w;
    }
  }
  #pragma unroll
  for (int u=0; u<8; ++u) part[ks][u][lane] = acc[u];
  __syncthreads();
  if (!valid) return;

  for (int idx=tid; idx<8*BB; idx+=256){
    int u = idx>>6, b = idx&63;
    int c = c0+u;
    float v = part[0][u][b] + part[1][u][b] + part[2][u][b] + part[3][u][b];
    if (isout){
      out[((size_t)b*TT + t)*DBX + c] = sigmf(v + bout[c]);
    } else {
      int u2 = c - DBX;
      int hh = u2 / PPH;
      int p  = u2 - hh*PPH;
      v += bupd[u2];
      if (p < MMM)            kvec_t[b*HS + p*NH + hh] = v;
      else if (p == MMM)      beta[b*NH+hh] = softplusf(v);
      else if (p == MMM+1)    gbuf[b*NH+hh] = sigmf(v);
      else if (p <  MMM+5)    shraw[(b*NH+hh)*3 + (p-(MMM+2))] = v;
      else if (p == MMM+5)    gam[b*NH+hh] = 1.0f + softplusf(v);
      else if (p <  2*MMM+6)  erase[b*HS + hh*MMM + (p-(MMM+6))] = sigmf(v);
      else                    addb[b*HS + hh*MMM + (p-(2*MMM+6))] = tanhf(v);
    }
  }
}

// ---------------- dots partial: 32 m-rows per block ----------------
// grid (BB, 4, 4): s = a-chunk, z = m-chunk
__global__ __launch_bounds__(512) void k_dotsP(
    const float* __restrict__ mem, const float* __restrict__ kvec_t,
    float* __restrict__ dpart, float* __restrict__ n2part)
{
  int b = blockIdx.x, s = blockIdx.y, z = blockIdx.z, tid = threadIdx.x;
  __shared__ __align__(16) float klt[128];  // 32 rows x 4 heads, [m][h]
  if (tid < 128) klt[tid] = kvec_t[b*HS + z*128 + tid];
  __syncthreads();
  int a = s*512 + tid;
  const float* mp = mem + (size_t)b*MMM*AAA + (size_t)(z*32)*AAA + a;
  const float4* k4 = (const float4*)klt;
  float a0=0,a1=0,a2=0,a3=0,n2=0;
  #pragma unroll 8
  for (int m=0; m<32; ++m){
    float mv = mp[(size_t)m*AAA];
    float4 kv = k4[m];
    a0 += kv.x*mv; a1 += kv.y*mv; a2 += kv.z*mv; a3 += kv.w*mv;
    n2 += mv*mv;
  }
  size_t base = ((size_t)(z*BB+b)*NH)*AAA + a;
  dpart[base]        = a0;
  dpart[base+AAA]    = a1;
  dpart[base+2*AAA]  = a2;
  dpart[base+3*AAA]  = a3;
  n2part[(size_t)(z*BB+b)*AAA + a] = n2;
}

// ---------------- dots finalize: knorm + sim + exp + wcsum ----------------
__global__ __launch_bounds__(512) void k_dotsF(
    const float* __restrict__ dpart, const float* __restrict__ n2part,
    const float* __restrict__ kvec_t, const float* __restrict__ beta,
    float* __restrict__ ebuf, float* __restrict__ wcsum)
{
  int b = blockIdx.x, s = blockIdx.y, tid = threadIdx.x;
  __shared__ float red[HS];
  __shared__ float kn[NH];
  __shared__ float rsum[8*NH];
  float kv = kvec_t[b*HS + tid];
  red[tid] = kv*kv;
  __syncthreads();
  #pragma unroll
  for (int off=256; off>=4; off>>=1){
    if (tid < off) red[tid] += red[tid+off];
    __syncthreads();
  }
  if (tid < NH) kn[tid] = sqrtf(red[tid]);
  __syncthreads();

  int a = s*512 + tid;
  float d[NH] = {0,0,0,0};
  float n2 = 0.0f;
  #pragma unroll
  for (int z=0; z<4; ++z){
    size_t base = ((size_t)(z*BB+b)*NH)*AAA + a;
    d[0] += dpart[base];
    d[1] += dpart[base+AAA];
    d[2] += dpart[base+2*AAA];
    d[3] += dpart[base+3*AAA];
    n2   += n2part[(size_t)(z*BB+b)*AAA + a];
  }
  float mn = sqrtf(n2);
  int wid = tid >> 6, lane = tid & 63;
  #pragma unroll
  for (int hh=0; hh<NH; ++hh){
    float sim = d[hh]/(kn[hh]*mn + EPSF);
    float e = expf(beta[b*NH+hh]*sim);
    ebuf[((size_t)(b*NH+hh))*AAA + a] = e;
    float v = e;
    #pragma unroll
    for (int off=32; off>0; off>>=1) v += __shfl_xor(v, off);
    if (lane==0) rsum[wid*NH+hh] = v;
  }
  __syncthreads();
  if (tid < NH){
    float s2 = 0.0f;
    #pragma unroll
    for (int w=0; w<8; ++w) s2 += rsum[w*NH+tid];
    atomicAdd(&wcsum[b*NH+tid], s2);
  }
}

// ---------------- normalize + interpolate + shift + sharpen (+ zero readTn) ----------------
__global__ __launch_bounds__(512) void k_shift(
    const float* __restrict__ ebuf, const float* __restrict__ wcsum,
    const float* __restrict__ gbuf, const float* __restrict__ shraw,
    const float* __restrict__ gam, const float* __restrict__ wt,
    float* __restrict__ wpb, float* __restrict__ wpsum, float* __restrict__ readTn)
{
  int b = blockIdx.x, s = blockIdx.y, tid = threadIdx.x;
  int a = s*512 + tid;
  int am1 = (a + AAA - 1) & (AAA-1);
  int ap1 = (a + 1) & (AAA-1);
  __shared__ float sh[NH*3], gl[NH], gml[NH], winv[NH];
  __shared__ float rsum[8*NH];
  if (s == 0) readTn[(size_t)tid*BB + b] = 0.0f;   // zero next-step read accumulator
  if (tid < NH){
    int hh = tid;
    float s0=shraw[(b*NH+hh)*3], s1=shraw[(b*NH+hh)*3+1], s2=shraw[(b*NH+hh)*3+2];
    float mx = fmaxf(s0, fmaxf(s1, s2));
    float e0=expf(s0-mx), e1=expf(s1-mx), e2=expf(s2-mx);
    float inv = 1.0f/(e0+e1+e2);
    sh[hh*3+0]=e0*inv; sh[hh*3+1]=e1*inv; sh[hh*3+2]=e2*inv;
    gl[hh]  = gbuf[b*NH+hh];
    gml[hh] = gam[b*NH+hh];
    winv[hh]= 1.0f/wcsum[b*NH+hh];
  }
  __syncthreads();
  int wid = tid >> 6, lane = tid & 63;
  #pragma unroll
  for (int hh=0; hh<NH; ++hh){
    const float* eb = ebuf + ((size_t)(b*NH+hh))*AAA;
    const float* wb = wt   + ((size_t)(b*NH+hh))*AAA;
    float inv = winv[hh], g = gl[hh];
    float s0 = sh[hh*3+0], s1 = sh[hh*3+1], s2 = sh[hh*3+2];
    float wgm1 = g*eb[am1]*inv + (1.0f-g)*wb[am1];
    float wg0  = g*eb[a]  *inv + (1.0f-g)*wb[a];
    float wgp1 = g*eb[ap1]*inv + (1.0f-g)*wb[ap1];
    float ws = s0*wgp1 + s1*wg0 + s2*wgm1;
    float wp = powf(ws + EPSF, gml[hh]);
    wpb[((size_t)(b*NH+hh))*AAA + a] = wp;
    float v = wp;
    #pragma unroll
    for (int off=32; off>0; off>>=1) v += __shfl_xor(v, off);
    if (lane==0) rsum[wid*NH+hh] = v;
  }
  __syncthreads();
  if (tid < NH){
    float s3 = 0.0f;
    #pragma unroll
    for (int w=0; w<8; ++w) s3 += rsum[w*NH+tid];
    atomicAdd(&wpsum[b*NH+tid], s3);
  }
}

// ---------------- updA: wt_new + mem erase/add over 32 m-rows ----------------
// grid (BB, 4, 4): s = a-chunk, z = m-chunk
__global__ __launch_bounds__(512) void k_updA(
    float* __restrict__ mem, const float* __restrict__ wpb, const float* __restrict__ wpsum,
    const float* __restrict__ erase, const float* __restrict__ addb,
    float* __restrict__ wt)
{
  int b = blockIdx.x, s = blockIdx.y, z = blockIdx.z, tid = threadIdx.x;
  int a = s*512 + tid;
  __shared__ __align__(16) float ert[128];   // 32 rows x 4 heads, [m][h]
  __shared__ __align__(16) float adt[128];
  if (tid < 128){
    int m = tid >> 2, hh = tid & 3;
    ert[tid] = erase[b*HS + hh*MMM + z*32 + m];
    adt[tid] = addb [b*HS + hh*MMM + z*32 + m];
  }
  float wtn[NH];
  #pragma unroll
  for (int hh=0; hh<NH; ++hh){
    float w = wpb[((size_t)(b*NH+hh))*AAA + a] / wpsum[b*NH+hh];
    wtn[hh] = w;
    if (z == 0) wt[((size_t)(b*NH+hh))*AAA + a] = w;
  }
  __syncthreads();

  float* mp = mem + (size_t)b*MMM*AAA + (size_t)(z*32)*AAA + a;
  const float4* e4 = (const float4*)ert;
  const float4* a4 = (const float4*)adt;
  #pragma unroll 8
  for (int m=0; m<32; ++m){
    float mv = mp[(size_t)m*AAA];
    float4 ev = e4[m], av = a4[m];
    float et = (1.0f - ev.x*wtn[0]) * (1.0f - ev.y*wtn[1])
             * (1.0f - ev.z*wtn[2]) * (1.0f - ev.w*wtn[3]);
    float at = av.x*wtn[0] + av.y*wtn[1] + av.z*wtn[2] + av.w*wtn[3];
    mp[(size_t)m*AAA] = mv*et + at;
  }
}

// ---------------- updB: read[b,h,m] einsum, wave owns rows m and m+64 ----------------
// grid (BB, 8), block 512 = 8 waves
__global__ __launch_bounds__(512) void k_updB(
    const float* __restrict__ mem, const float* __restrict__ wt,
    float* __restrict__ readTn)
{
  int b = blockIdx.x, my = blockIdx.y, tid = threadIdx.x;
  int wave = tid >> 6, lane = tid & 63;
  int m0 = my*8 + wave;         // 0..63
  int m1 = m0 + 64;             // 64..127
  const float* row0 = mem + (size_t)b*MMM*AAA + (size_t)m0*AAA;
  const float* row1 = mem + (size_t)b*MMM*AAA + (size_t)m1*AAA;
  const float* w0 = wt + ((size_t)(b*NH+0))*AAA;
  const float* w1 = wt + ((size_t)(b*NH+1))*AAA;
  const float* w2 = wt + ((size_t)(b*NH+2))*AAA;
  const float* w3 = wt + ((size_t)(b*NH+3))*AAA;
  float r00=0,r01=0,r02=0,r03=0, r10=0,r11=0,r12=0,r13=0;
  #pragma unroll 4
  for (int it=0; it<32; ++it){
    int a = it*64 + lane;
    float mv0 = row0[a], mv1 = row1[a];
    float wv0 = w0[a], wv1 = w1[a], wv2 = w2[a], wv3 = w3[a];
    r00 += mv0*wv0; r01 += mv0*wv1; r02 += mv0*wv2; r03 += mv0*wv3;
    r10 += mv1*wv0; r11 += mv1*wv1; r12 += mv1*wv2; r13 += mv1*wv3;
  }
  float rr[2][NH] = {{r00,r01,r02,r03},{r10,r11,r12,r13}};
  #pragma unroll
  for (int q=0; q<2; ++q){
    #pragma unroll
    for (int hh=0; hh<NH; ++hh){
      float v = rr[q][hh];
      #pragma unroll
      for (int off=32; off>0; off>>=1) v += __shfl_xor(v, off);
      rr[q][hh] = v;
    }
  }
  if (lane == 0){
    #pragma unroll
    for (int hh=0; hh<NH; ++hh){
      readTn[(size_t)(hh*MMM+m0)*BB + b] = rr[0][hh];
      readTn[(size_t)(hh*MMM+m1)*BB + b] = rr[1][hh];
    }
  }
}

extern "C" void kernel_launch(void* const* d_in, const int* in_sizes, int n_in,
                              void* d_out, int out_size, void* d_ws, size_t ws_size,
                              hipStream_t stream){
  const float* x    = (const float*)d_in[0];
  const float* Wst  = (const float*)d_in[1];
  const float* bst  = (const float*)d_in[2];
  const float* Wout = (const float*)d_in[3];
  const float* bout = (const float*)d_in[4];
  const float* Wupd = (const float*)d_in[5];
  const float* bupd = (const float*)d_in[6];
  float* out = (float*)d_out;

  float* p = (float*)d_ws;
  float* hT     = p; p += 2*HS*BB;            // ping-pong h, [j][b]
  float* readT  = p; p += 2*HS*BB;            // ping-pong read, [(h,m)][b]
  float* hpart  = p; p += KSPL*HS*BB;         // split-K partials (1 MB)
  float* xT     = p; p += (size_t)TT*IND*BB;  // transposed x (8.65 MB)
  float* wt     = p; p += BB*NH*AAA;
  float* mem    = p; p += (size_t)BB*MMM*AAA;
  float* kvec_t = p; p += BB*HS;
  float* beta   = p; p += BB*NH;
  float* gbuf   = p; p += BB*NH;
  float* gam    = p; p += BB*NH;
  float* shraw  = p; p += BB*NH*3;
  float* erase  = p; p += BB*HS;
  float* addb   = p; p += BB*HS;
  float* ebuf   = p; p += BB*NH*AAA;
  float* wpb    = p; p += 4*(size_t)BB*NH*AAA; // 8.4 MB: doubles as k_dots dpart
  float* n2part = p; p += 4*BB*AAA;            // 2 MB
  float* wcsum  = p; p += BB*NH;
  float* wpsum  = p; p += BB*NH;
  float* dpart  = wpb;                         // alias: dpart consumed before wpb written

  k_init<<<2048, 256, 0, stream>>>(hT, readT, wt, mem);
  k_tx<<<BB, 256, 0, stream>>>(x, xT);
  for (int t=0; t<TT; ++t){
    const float* hTp = hT    + (t&1)*HS*BB;
    float* hTn       = hT    + ((t+1)&1)*HS*BB;
    const float* rTp = readT + (t&1)*HS*BB;
    float* rTn       = readT + ((t+1)&1)*HS*BB;
    k1_state<<<dim3(32,KSPL), 256, 0, stream>>>(xT, Wst, hTp, rTp, hpart, wcsum, wpsum, t);
    k2h<<<64, 512, 0, stream>>>(hpart, bst, hTn);
    k2_outupd<<<dim3(259), 256, 0, stream>>>(hTn, Wout, bout, Wupd, bupd, out,
        kvec_t, beta, gbuf, gam, shraw, erase, addb, t);
    k_dotsP<<<dim3(BB,4,4), 512, 0, stream>>>(mem, kvec_t, dpart, n2part);
    k_dotsF<<<dim3(BB,4), 512, 0, stream>>>(dpart, n2part, kvec_t, beta, ebuf, wcsum);
    k_shift<<<dim3(BB,4), 512, 0, stream>>>(ebuf, wcsum, gbuf, shraw, gam, wt, wpb, wpsum, rTn);
    k_updA<<<dim3(BB,4,4), 512, 0, stream>>>(mem, wpb, wpsum, erase, addb, wt);
    k_updB<<<dim3(BB,8), 512, 0, stream>>>(mem, wt, rTn);
  }
}

// Round 14
// 10357.407 us; speedup vs baseline: 11.9019x; 1.1210x over previous
//
#include <hip/hip_runtime.h>
#include <math.h>

#define BB 64
#define TT 128
#define DBX 256
#define IND 264
#define HS 512
#define NH 4
#define MMM 128
#define AAA 2048
#define PPH 390
#define NCOLS (DBX + NH*PPH)   // 2072
#define KTOT (IND + HS + HS)   // 1288
#define KSPL 8                 // k1 split-K: 8 x 161
#define KCH  161
#define EPSF 1e-8f

__device__ __forceinline__ float sigmf(float x){ return 1.0f/(1.0f+expf(-x)); }
__device__ __forceinline__ float softplusf(float x){ return (x > 20.0f) ? x : log1pf(expf(x)); }

// ---------------- init ----------------
__global__ void k_init(float* __restrict__ hT, float* __restrict__ readT,
                       float* __restrict__ wt, float* __restrict__ mem){
  int i = blockIdx.x*blockDim.x + threadIdx.x;
  int stride = gridDim.x*blockDim.x;
  for (int idx=i; idx<BB*MMM*AAA; idx+=stride) mem[idx]=0.01f;
  for (int idx=i; idx<HS*BB; idx+=stride){ hT[idx]=1.0f; readT[idx]=0.01f; }
  for (int idx=i; idx<BB*NH*AAA; idx+=stride) wt[idx] = ((idx & (AAA-1))==0)?1.0f:0.0f;
}

// ---------------- transpose x[b][t][i] -> xT[t*IND+i][b] (once) ----------------
__global__ __launch_bounds__(256) void k_tx(const float* __restrict__ x, float* __restrict__ xT){
  int b = blockIdx.x;
  for (int f = threadIdx.x; f < TT*IND; f += 256)
    xT[(size_t)f*BB + b] = x[(size_t)b*TT*IND + f];
}

// ---------------- k1: split-K partial GEMM  hpart[ks][j][b] ----------------
__global__ __launch_bounds__(256) void k1_state(
    const float* __restrict__ xT, const float* __restrict__ Wst,
    const float* __restrict__ hTp, const float* __restrict__ readTp,
    float* __restrict__ hpart, float* __restrict__ wcsum, float* __restrict__ wpsum, int t)
{
  int tid = threadIdx.x, wave = tid>>6, lane = tid&63;
  int ks = blockIdx.y;
  int j0 = blockIdx.x*16 + wave*4;
  if (blockIdx.x==0 && ks==0){
    wcsum[tid] = 0.0f;   // BB*NH == 256
    wpsum[tid] = 0.0f;
  }
  float a0=0,a1=0,a2=0,a3=0;
  int k0 = ks*KCH, kend = k0+KCH;

  #define K1STEP(AEXPR) { float aV=(AEXPR); \
      float4 wv = *(const float4*)(Wst + (size_t)k*HS + j0); \
      a0 += aV*wv.x; a1 += aV*wv.y; a2 += aV*wv.z; a3 += aV*wv.w; }

  {int s = k0, e = kend<IND?kend:IND;
   #pragma unroll 4
   for (int k=s;k<e;++k) K1STEP(xT[((size_t)t*IND + k)*BB + lane]); }
  {int s = k0>IND?k0:IND, e = kend<(IND+HS)?kend:(IND+HS);
   #pragma unroll 4
   for (int k=s;k<e;++k) K1STEP(hTp[(k-IND)*BB + lane]); }
  {int s = k0>(IND+HS)?k0:(IND+HS), e = kend;
   #pragma unroll 4
   for (int k=s;k<e;++k) K1STEP(readTp[(k-IND-HS)*BB + lane]); }
  #undef K1STEP

  float* hp = hpart + (size_t)ks*HS*BB + (size_t)j0*BB + lane;
  hp[0]    = a0;
  hp[BB]   = a1;
  hp[2*BB] = a2;
  hp[3*BB] = a3;
}

// ---------------- k2h: reduce split-K partials -> h = sigmoid(. + b) ----------------
__global__ __launch_bounds__(512) void k2h(
    const float* __restrict__ hpart, const float* __restrict__ bst, float* __restrict__ hTn)
{
  int idx = blockIdx.x*512 + threadIdx.x;   // 64 blocks x 512 = 32768 = HS*BB
  float v = 0.0f;
  #pragma unroll
  for (int ks=0; ks<KSPL; ++ks) v += hpart[(size_t)ks*HS*BB + idx];
  hTn[idx] = sigmf(v + bst[idx>>6]);
}

// ---------------- k2: out/upd GEMM, split-K across 4 waves, + transforms ----------------
__global__ __launch_bounds__(256) void k2_outupd(
    const float* __restrict__ hTn,
    const float* __restrict__ Wout, const float* __restrict__ bout,
    const float* __restrict__ Wupd, const float* __restrict__ bupd,
    float* __restrict__ out,
    float* __restrict__ kvec_t, float* __restrict__ beta, float* __restrict__ gbuf,
    float* __restrict__ gam, float* __restrict__ shraw,
    float* __restrict__ erase, float* __restrict__ addb, int t)
{
  __shared__ float part[4][8][BB];
  int tid = threadIdx.x, ks = tid>>6, lane = tid&63;
  int c0 = blockIdx.x*8;
  bool isout = (c0 < DBX);
  size_t strd = isout ? (size_t)DBX : (size_t)(NH*PPH);
  const float* wbase = isout ? (Wout + c0) : (Wupd + (c0 - DBX));
  bool valid = (c0 < NCOLS);

  float acc[8] = {0,0,0,0,0,0,0,0};
  if (valid){
    int k0 = ks*128;
    #pragma unroll 4
    for (int k=k0; k<k0+128; ++k){
      float a = hTn[k*BB + lane];
      const float4* w4 = (const float4*)(wbase + (size_t)k*strd);
      float4 wa = w4[0], wb = w4[1];
      acc[0]+=a*wa.x; acc[1]+=a*wa.y; acc[2]+=a*wa.z; acc[3]+=a*wa.w;
      acc[4]+=a*wb.x; acc[5]+=a*wb.y; acc[6]+=a*wb.z; acc[7]+=a*wb.w;
    }
  }
  #pragma unroll
  for (int u=0; u<8; ++u) part[ks][u][lane] = acc[u];
  __syncthreads();
  if (!valid) return;

  for (int idx=tid; idx<8*BB; idx+=256){
    int u = idx>>6, b = idx&63;
    int c = c0+u;
    float v = part[0][u][b] + part[1][u][b] + part[2][u][b] + part[3][u][b];
    if (isout){
      out[((size_t)b*TT + t)*DBX + c] = sigmf(v + bout[c]);
    } else {
      int u2 = c - DBX;
      int hh = u2 / PPH;
      int p  = u2 - hh*PPH;
      v += bupd[u2];
      if (p < MMM)            kvec_t[b*HS + p*NH + hh] = v;
      else if (p == MMM)      beta[b*NH+hh] = softplusf(v);
      else if (p == MMM+1)    gbuf[b*NH+hh] = sigmf(v);
      else if (p <  MMM+5)    shraw[(b*NH+hh)*3 + (p-(MMM+2))] = v;
      else if (p == MMM+5)    gam[b*NH+hh] = 1.0f + softplusf(v);
      else if (p <  2*MMM+6)  erase[b*HS + hh*MMM + (p-(MMM+6))] = sigmf(v);
      else                    addb[b*HS + hh*MMM + (p-(2*MMM+6))] = tanhf(v);
    }
  }
}

// ---------------- dots partial: 32 m-rows per block ----------------
// grid (BB, 4, 4): s = a-chunk, z = m-chunk
__global__ __launch_bounds__(512) void k_dotsP(
    const float* __restrict__ mem, const float* __restrict__ kvec_t,
    float* __restrict__ dpart, float* __restrict__ n2part)
{
  int b = blockIdx.x, s = blockIdx.y, z = blockIdx.z, tid = threadIdx.x;
  __shared__ __align__(16) float klt[128];  // 32 rows x 4 heads, [m][h]
  if (tid < 128) klt[tid] = kvec_t[b*HS + z*128 + tid];
  __syncthreads();
  int a = s*512 + tid;
  const float* mp = mem + (size_t)b*MMM*AAA + (size_t)(z*32)*AAA + a;
  const float4* k4 = (const float4*)klt;
  float a0=0,a1=0,a2=0,a3=0,n2=0;
  #pragma unroll 8
  for (int m=0; m<32; ++m){
    float mv = mp[(size_t)m*AAA];
    float4 kv = k4[m];
    a0 += kv.x*mv; a1 += kv.y*mv; a2 += kv.z*mv; a3 += kv.w*mv;
    n2 += mv*mv;
  }
  size_t base = ((size_t)(z*BB+b)*NH)*AAA + a;
  dpart[base]        = a0;
  dpart[base+AAA]    = a1;
  dpart[base+2*AAA]  = a2;
  dpart[base+3*AAA]  = a3;
  n2part[(size_t)(z*BB+b)*AAA + a] = n2;
}

// ---------------- dots finalize: knorm + sim + exp + wcsum ----------------
__global__ __launch_bounds__(512) void k_dotsF(
    const float* __restrict__ dpart, const float* __restrict__ n2part,
    const float* __restrict__ kvec_t, const float* __restrict__ beta,
    float* __restrict__ ebuf, float* __restrict__ wcsum)
{
  int b = blockIdx.x, s = blockIdx.y, tid = threadIdx.x;
  __shared__ float red[HS];
  __shared__ float kn[NH];
  __shared__ float rsum[8*NH];
  float kv = kvec_t[b*HS + tid];
  red[tid] = kv*kv;
  __syncthreads();
  #pragma unroll
  for (int off=256; off>=4; off>>=1){
    if (tid < off) red[tid] += red[tid+off];
    __syncthreads();
  }
  if (tid < NH) kn[tid] = sqrtf(red[tid]);
  __syncthreads();

  int a = s*512 + tid;
  float d[NH] = {0,0,0,0};
  float n2 = 0.0f;
  #pragma unroll
  for (int z=0; z<4; ++z){
    size_t base = ((size_t)(z*BB+b)*NH)*AAA + a;
    d[0] += dpart[base];
    d[1] += dpart[base+AAA];
    d[2] += dpart[base+2*AAA];
    d[3] += dpart[base+3*AAA];
    n2   += n2part[(size_t)(z*BB+b)*AAA + a];
  }
  float mn = sqrtf(n2);
  int wid = tid >> 6, lane = tid & 63;
  #pragma unroll
  for (int hh=0; hh<NH; ++hh){
    float sim = d[hh]/(kn[hh]*mn + EPSF);
    float e = expf(beta[b*NH+hh]*sim);
    ebuf[((size_t)(b*NH+hh))*AAA + a] = e;
    float v = e;
    #pragma unroll
    for (int off=32; off>0; off>>=1) v += __shfl_xor(v, off);
    if (lane==0) rsum[wid*NH+hh] = v;
  }
  __syncthreads();
  if (tid < NH){
    float s2 = 0.0f;
    #pragma unroll
    for (int w=0; w<8; ++w) s2 += rsum[w*NH+tid];
    atomicAdd(&wcsum[b*NH+tid], s2);
  }
}

// ---------------- normalize + interpolate + shift + sharpen ----------------
__global__ __launch_bounds__(512) void k_shift(
    const float* __restrict__ ebuf, const float* __restrict__ wcsum,
    const float* __restrict__ gbuf, const float* __restrict__ shraw,
    const float* __restrict__ gam, const float* __restrict__ wt,
    float* __restrict__ wpb, float* __restrict__ wpsum)
{
  int b = blockIdx.x, s = blockIdx.y, tid = threadIdx.x;
  int a = s*512 + tid;
  int am1 = (a + AAA - 1) & (AAA-1);
  int ap1 = (a + 1) & (AAA-1);
  __shared__ float sh[NH*3], gl[NH], gml[NH], winv[NH];
  __shared__ float rsum[8*NH];
  if (tid < NH){
    int hh = tid;
    float s0=shraw[(b*NH+hh)*3], s1=shraw[(b*NH+hh)*3+1], s2=shraw[(b*NH+hh)*3+2];
    float mx = fmaxf(s0, fmaxf(s1, s2));
    float e0=expf(s0-mx), e1=expf(s1-mx), e2=expf(s2-mx);
    float inv = 1.0f/(e0+e1+e2);
    sh[hh*3+0]=e0*inv; sh[hh*3+1]=e1*inv; sh[hh*3+2]=e2*inv;
    gl[hh]  = gbuf[b*NH+hh];
    gml[hh] = gam[b*NH+hh];
    winv[hh]= 1.0f/wcsum[b*NH+hh];
  }
  __syncthreads();
  int wid = tid >> 6, lane = tid & 63;
  #pragma unroll
  for (int hh=0; hh<NH; ++hh){
    const float* eb = ebuf + ((size_t)(b*NH+hh))*AAA;
    const float* wb = wt   + ((size_t)(b*NH+hh))*AAA;
    float inv = winv[hh], g = gl[hh];
    float s0 = sh[hh*3+0], s1 = sh[hh*3+1], s2 = sh[hh*3+2];
    float wgm1 = g*eb[am1]*inv + (1.0f-g)*wb[am1];
    float wg0  = g*eb[a]  *inv + (1.0f-g)*wb[a];
    float wgp1 = g*eb[ap1]*inv + (1.0f-g)*wb[ap1];
    float ws = s0*wgp1 + s1*wg0 + s2*wgm1;
    float wp = powf(ws + EPSF, gml[hh]);
    wpb[((size_t)(b*NH+hh))*AAA + a] = wp;
    float v = wp;
    #pragma unroll
    for (int off=32; off>0; off>>=1) v += __shfl_xor(v, off);
    if (lane==0) rsum[wid*NH+hh] = v;
  }
  __syncthreads();
  if (tid < NH){
    float s3 = 0.0f;
    #pragma unroll
    for (int w=0; w<8; ++w) s3 += rsum[w*NH+tid];
    atomicAdd(&wpsum[b*NH+tid], s3);
  }
}

// ---------------- updAB: row-wise fused wt_new + mem erase/add + read einsum ----------------
// grid (BB, 8), block 512 = 8 waves. Wave owns rows m0 = my*8+wave and m1 = m0+64.
// wtn staged in LDS [a][h] (32KB, conflict-free b128 reads); direct readTn writes.
__global__ __launch_bounds__(512) void k_updAB(
    float* __restrict__ mem, const float* __restrict__ wpb, const float* __restrict__ wpsum,
    const float* __restrict__ erase, const float* __restrict__ addb,
    float* __restrict__ wt, float* __restrict__ readTn)
{
  __shared__ __align__(16) float wl[AAA*4];   // [a][h], 32 KB
  int b = blockIdx.x, my = blockIdx.y, tid = threadIdx.x;
  int wave = tid >> 6, lane = tid & 63;
  float winv[4];
  #pragma unroll
  for (int h=0;h<4;++h) winv[h] = 1.0f/wpsum[b*NH+h];
  // phase 0: wtn -> LDS (+ global wt, my==0 blocks only)
  #pragma unroll
  for (int c4=0;c4<4;++c4){
    int a = c4*512 + tid;
    float w0 = wpb[((size_t)(b*NH+0))*AAA + a]*winv[0];
    float w1 = wpb[((size_t)(b*NH+1))*AAA + a]*winv[1];
    float w2 = wpb[((size_t)(b*NH+2))*AAA + a]*winv[2];
    float w3 = wpb[((size_t)(b*NH+3))*AAA + a]*winv[3];
    wl[a*4+0]=w0; wl[a*4+1]=w1; wl[a*4+2]=w2; wl[a*4+3]=w3;
    if (my == 0){
      wt[((size_t)(b*NH+0))*AAA + a] = w0;
      wt[((size_t)(b*NH+1))*AAA + a] = w1;
      wt[((size_t)(b*NH+2))*AAA + a] = w2;
      wt[((size_t)(b*NH+3))*AAA + a] = w3;
    }
  }
  __syncthreads();

  int m0 = my*8 + wave, m1 = m0 + 64;
  float er0[4], ad0[4], er1[4], ad1[4];
  #pragma unroll
  for (int h=0;h<4;++h){
    er0[h] = erase[b*HS + h*MMM + m0];
    ad0[h] = addb [b*HS + h*MMM + m0];
    er1[h] = erase[b*HS + h*MMM + m1];
    ad1[h] = addb [b*HS + h*MMM + m1];
  }
  float* row0 = mem + (size_t)b*MMM*AAA + (size_t)m0*AAA;
  float* row1 = mem + (size_t)b*MMM*AAA + (size_t)m1*AAA;
  const float4* wl4 = (const float4*)wl;
  float r00=0,r01=0,r02=0,r03=0, r10=0,r11=0,r12=0,r13=0;
  #pragma unroll 4
  for (int it=0; it<32; ++it){
    int a = it*64 + lane;
    float mv0 = row0[a], mv1 = row1[a];
    float4 w4 = wl4[a];
    float et0 = (1.0f - er0[0]*w4.x)*(1.0f - er0[1]*w4.y)
              * (1.0f - er0[2]*w4.z)*(1.0f - er0[3]*w4.w);
    float at0 = ad0[0]*w4.x + ad0[1]*w4.y + ad0[2]*w4.z + ad0[3]*w4.w;
    float n0 = mv0*et0 + at0;
    row0[a] = n0;
    r00 += n0*w4.x; r01 += n0*w4.y; r02 += n0*w4.z; r03 += n0*w4.w;
    float et1 = (1.0f - er1[0]*w4.x)*(1.0f - er1[1]*w4.y)
              * (1.0f - er1[2]*w4.z)*(1.0f - er1[3]*w4.w);
    float at1 = ad1[0]*w4.x + ad1[1]*w4.y + ad1[2]*w4.z + ad1[3]*w4.w;
    float n1 = mv1*et1 + at1;
    row1[a] = n1;
    r10 += n1*w4.x; r11 += n1*w4.y; r12 += n1*w4.z; r13 += n1*w4.w;
  }
  float rr[2][NH] = {{r00,r01,r02,r03},{r10,r11,r12,r13}};
  #pragma unroll
  for (int q=0; q<2; ++q){
    #pragma unroll
    for (int hh=0; hh<NH; ++hh){
      float v = rr[q][hh];
      #pragma unroll
      for (int off=32; off>0; off>>=1) v += __shfl_xor(v, off);
      rr[q][hh] = v;
    }
  }
  if (lane == 0){
    #pragma unroll
    for (int hh=0; hh<NH; ++hh){
      readTn[(size_t)(hh*MMM+m0)*BB + b] = rr[0][hh];
      readTn[(size_t)(hh*MMM+m1)*BB + b] = rr[1][hh];
    }
  }
}

extern "C" void kernel_launch(void* const* d_in, const int* in_sizes, int n_in,
                              void* d_out, int out_size, void* d_ws, size_t ws_size,
                              hipStream_t stream){
  const float* x    = (const float*)d_in[0];
  const float* Wst  = (const float*)d_in[1];
  const float* bst  = (const float*)d_in[2];
  const float* Wout = (const float*)d_in[3];
  const float* bout = (const float*)d_in[4];
  const float* Wupd = (const float*)d_in[5];
  const float* bupd = (const float*)d_in[6];
  float* out = (float*)d_out;

  float* p = (float*)d_ws;
  float* hT     = p; p += 2*HS*BB;            // ping-pong h, [j][b]
  float* readT  = p; p += 2*HS*BB;            // ping-pong read, [(h,m)][b]
  float* hpart  = p; p += KSPL*HS*BB;         // split-K partials (1 MB)
  float* xT     = p; p += (size_t)TT*IND*BB;  // transposed x (8.65 MB)
  float* wt     = p; p += BB*NH*AAA;
  float* mem    = p; p += (size_t)BB*MMM*AAA;
  float* kvec_t = p; p += BB*HS;
  float* beta   = p; p += BB*NH;
  float* gbuf   = p; p += BB*NH;
  float* gam    = p; p += BB*NH;
  float* shraw  = p; p += BB*NH*3;
  float* erase  = p; p += BB*HS;
  float* addb   = p; p += BB*HS;
  float* ebuf   = p; p += BB*NH*AAA;
  float* wpb    = p; p += 4*(size_t)BB*NH*AAA; // 8.4 MB: doubles as k_dots dpart
  float* n2part = p; p += 4*BB*AAA;            // 2 MB
  float* wcsum  = p; p += BB*NH;
  float* wpsum  = p; p += BB*NH;
  float* dpart  = wpb;                         // alias: dpart consumed before wpb written

  k_init<<<2048, 256, 0, stream>>>(hT, readT, wt, mem);
  k_tx<<<BB, 256, 0, stream>>>(x, xT);
  for (int t=0; t<TT; ++t){
    const float* hTp = hT    + (t&1)*HS*BB;
    float* hTn       = hT    + ((t+1)&1)*HS*BB;
    const float* rTp = readT + (t&1)*HS*BB;
    float* rTn       = readT + ((t+1)&1)*HS*BB;
    k1_state<<<dim3(32,KSPL), 256, 0, stream>>>(xT, Wst, hTp, rTp, hpart, wcsum, wpsum, t);
    k2h<<<64, 512, 0, stream>>>(hpart, bst, hTn);
    k2_outupd<<<dim3(259), 256, 0, stream>>>(hTn, Wout, bout, Wupd, bupd, out,
        kvec_t, beta, gbuf, gam, shraw, erase, addb, t);
    k_dotsP<<<dim3(BB,4,4), 512, 0, stream>>>(mem, kvec_t, dpart, n2part);
    k_dotsF<<<dim3(BB,4), 512, 0, stream>>>(dpart, n2part, kvec_t, beta, ebuf, wcsum);
    k_shift<<<dim3(BB,4), 512, 0, stream>>>(ebuf, wcsum, gbuf, shraw, gam, wt, wpb, wpsum);
    k_updAB<<<dim3(BB,8), 512, 0, stream>>>(mem, wpb, wpsum, erase, addb, wt, rTn);
  }
}